// Round 3
// baseline (5467.587 us; speedup 1.0000x reference)
//
#include <hip/hip_runtime.h>
#include <cstdint>
#include <cstddef>

#define T_LEN 4096
#define C_DIM 256
#define B_DIM 8
#define K_TOP 4

__device__ __forceinline__ float gelu_exact(float x) {
    return 0.5f * x * (1.0f + erff(x * 0.70710678118654752f));
}

// ------------------------------------------------------------------
// out = x   (fp32, float4 vectorized)
// ------------------------------------------------------------------
__global__ __launch_bounds__(256) void copy_x_kernel(const float4* __restrict__ x,
                                                     float4* __restrict__ out) {
    size_t i = (size_t)blockIdx.x * 256 + threadIdx.x;
    out[i] = x[i];
}

// ------------------------------------------------------------------
// Per-(b,c) 4096-pt radix-2 DIT FFT in LDS; write |X_f| for f=1..2048
// mags layout: [b][c][2048]  (coalesced writes, coalesced reduce reads)
// ------------------------------------------------------------------
__global__ __launch_bounds__(256) void fft_mag_kernel(const float* __restrict__ x,
                                                      float* __restrict__ mags) {
    const int bx = blockIdx.x;
    const int b = bx >> 8;
    const int c = bx & 255;
    const int tid = threadIdx.x;

    __shared__ __align__(16) float re[4096];
    __shared__ __align__(16) float im[4096];
    __shared__ __align__(16) float twr[2048];
    __shared__ __align__(16) float twi[2048];

    // twiddle table: W[u] = exp(-2*pi*i*u/4096)
    for (int u = tid; u < 2048; u += 256) {
        float ang = -6.283185307179586f * (float)u / 4096.0f;
        float s, co;
        sincosf(ang, &s, &co);
        twr[u] = co;
        twi[u] = s;
    }
    // load input in bit-reversed order (12-bit reverse)
    const float* xp = x + (size_t)b * T_LEN * C_DIM + c;
    for (int e = tid; e < 4096; e += 256) {
        int r = (int)(__brev((unsigned)e) >> 20);
        re[r] = xp[(size_t)e * C_DIM];
        im[e] = 0.0f;
    }
    __syncthreads();

    for (int s = 1; s <= 12; s++) {
        const int half = 1 << (s - 1);
        const int shift = 12 - s;
        for (int j = tid; j < 2048; j += 256) {
            int p = j & (half - 1);
            int g = j >> (s - 1);
            int i1 = (g << s) + p;
            int i2 = i1 + half;
            float wr = twr[p << shift];
            float wi = twi[p << shift];
            float r2 = re[i2], q2 = im[i2];
            float tr = wr * r2 - wi * q2;
            float ti = wr * q2 + wi * r2;
            float r1 = re[i1], q1 = im[i1];
            re[i2] = r1 - tr;
            im[i2] = q1 - ti;
            re[i1] = r1 + tr;
            im[i1] = q1 + ti;
        }
        __syncthreads();
    }

    float* mp = mags + ((size_t)(b * C_DIM + c)) * 2048;
    for (int u = tid; u < 2048; u += 256) {
        int f = u + 1;  // drop DC, bins 1..2048
        mp[u] = sqrtf(re[f] * re[f] + im[f] * im[f]);
    }
}

// ------------------------------------------------------------------
// amps[b][u] = mean over c of mags[b][c][u]   (deterministic order)
// ------------------------------------------------------------------
__global__ __launch_bounds__(256) void reduce_amps_kernel(const float* __restrict__ mags,
                                                          float* __restrict__ amps) {
    const int b = blockIdx.y;
    const int u = blockIdx.x * 256 + threadIdx.x;
    const float* mp = mags + (size_t)b * C_DIM * 2048 + u;
    float s = 0.0f;
    for (int c = 0; c < C_DIM; c++) s += mp[(size_t)c * 2048];
    amps[b * 2048 + u] = s * (1.0f / (float)C_DIM);
}

// ------------------------------------------------------------------
// Per-batch top-4 (value desc, ties -> lower index), periods, softmax w
// ------------------------------------------------------------------
__global__ __launch_bounds__(256) void topk_kernel(const float* __restrict__ amps,
                                                   int* __restrict__ meta_p,
                                                   float* __restrict__ meta_w) {
    const int b = blockIdx.x;
    const int tid = threadIdx.x;
    __shared__ float v[2048];
    __shared__ float rv[256];
    __shared__ int ri[256];
    __shared__ float topv[K_TOP];
    __shared__ int topi[K_TOP];

    for (int u = tid; u < 2048; u += 256) v[u] = amps[b * 2048 + u];

    for (int k = 0; k < K_TOP; k++) {
        __syncthreads();
        float bv = -1e30f;
        int bi = 2048;
        for (int u = tid; u < 2048; u += 256) {
            float val = v[u];
            if (val > bv) { bv = val; bi = u; }  // ascending scan keeps lowest idx on tie
        }
        rv[tid] = bv;
        ri[tid] = bi;
        __syncthreads();
        for (int s = 128; s > 0; s >>= 1) {
            if (tid < s) {
                float ov = rv[tid + s];
                int oi = ri[tid + s];
                if (ov > rv[tid] || (ov == rv[tid] && oi < ri[tid])) {
                    rv[tid] = ov;
                    ri[tid] = oi;
                }
            }
            __syncthreads();
        }
        if (tid == 0) {
            topv[k] = rv[0];
            topi[k] = ri[0];
            v[ri[0]] = -1e30f;
        }
    }
    __syncthreads();
    if (tid == 0) {
        float mx = topv[0];
        for (int k = 1; k < K_TOP; k++) mx = fmaxf(mx, topv[k]);
        float e[K_TOP], se = 0.0f;
        for (int k = 0; k < K_TOP; k++) { e[k] = expf(topv[k] - mx); se += e[k]; }
        for (int k = 0; k < K_TOP; k++) {
            int idx = topi[k];
            int d = (idx >= 1) ? idx : 1;
            int p = T_LEN / d;
            if (p < 1) p = 1;
            meta_p[b * K_TOP + k] = p;
            meta_w[b * K_TOP + k] = e[k] / se;
        }
    }
}

// ------------------------------------------------------------------
// Conv 3x3 (SAME, masked fold geometry) + bias + exact GELU, unfolded
// directly into convbuf[b][t][c].  One block: 8 timesteps x 256 c_out.
// LDS stages the 9-neighbor input vectors in ci-chunks of 128:
//   g[q][ci(128)][tt(8)]  -> broadcast ds_read_b128 in the main loop.
// ------------------------------------------------------------------
__global__ __launch_bounds__(256) void conv_kernel(const float* __restrict__ x,
                                                   const float* __restrict__ Wc,
                                                   const float* __restrict__ bc,
                                                   const int* __restrict__ meta_p,
                                                   float* __restrict__ convbuf,
                                                   int k) {
    const int b = blockIdx.y;
    const int n = meta_p[b * K_TOP + k];
    const int m = (T_LEN + n - 1) / n;
    const int t0 = blockIdx.x * 8;
    const int tid = threadIdx.x;

    __shared__ __align__(16) float g[9 * 128 * 8];  // 36 KB

    int i8[8], j8[8];
#pragma unroll
    for (int tt = 0; tt < 8; tt++) {
        int t = t0 + tt;
        int ii = t / n;
        i8[tt] = ii;
        j8[tt] = t - ii * n;
    }

    float acc[8] = {0.f, 0.f, 0.f, 0.f, 0.f, 0.f, 0.f, 0.f};
    const float* Wcp = Wc + tid;  // c_out = tid

    for (int cc = 0; cc < 2; cc++) {
        __syncthreads();  // protect g from previous chunk's readers
        {
            const int ci = tid & 127;
            const int pr = tid >> 7;
            for (int vq = pr; vq < 72; vq += 2) {
                int q = vq >> 3;
                int tt = vq & 7;
                int di = q / 3 - 1;
                int dj = q % 3 - 1;
                int ii = i8[tt] + di;
                int jj = j8[tt] + dj;
                float val = 0.0f;
                if (ii >= 0 && jj >= 0 && jj < n && ii < m) {
                    int tp = ii * n + jj;
                    if (tp < T_LEN)
                        val = x[((size_t)(b * T_LEN) + tp) * C_DIM + cc * 128 + ci];
                }
                g[(q * 128 + ci) * 8 + tt] = val;
            }
        }
        __syncthreads();

        for (int q = 0; q < 9; q++) {
            const float* wq = Wcp + (size_t)(q * C_DIM + cc * 128) * C_DIM;
            const float* gq = &g[q * 128 * 8];
#pragma unroll 4
            for (int ci2 = 0; ci2 < 128; ci2++) {
                float av[8];
                *(float4*)&av[0] = *(const float4*)&gq[ci2 * 8];
                *(float4*)&av[4] = *(const float4*)&gq[ci2 * 8 + 4];
                float wv = wq[(size_t)ci2 * C_DIM];
#pragma unroll
                for (int rr = 0; rr < 8; rr++) acc[rr] += av[rr] * wv;
            }
        }
    }

    const float bias = bc[tid];
    float* op = convbuf + ((size_t)(b * T_LEN) + t0) * C_DIM + tid;
#pragma unroll
    for (int tt = 0; tt < 8; tt++) {
        float y = acc[tt] + bias;
        op[(size_t)tt * C_DIM] = gelu_exact(y);
    }
}

// ------------------------------------------------------------------
// FeedForward for one k: h = gelu(row@W1+b1)@W2+b2 ; out += w_k * h
// Block: 16 rows x 256 threads. A[256ci][16r] and H[1024h][16r] in LDS,
// broadcast float4 reads in both GEMV phases.
// ------------------------------------------------------------------
__global__ __launch_bounds__(256) void ff_kernel(const float* __restrict__ convbuf,
                                                 const float* __restrict__ W1,
                                                 const float* __restrict__ b1,
                                                 const float* __restrict__ W2,
                                                 const float* __restrict__ b2,
                                                 const float* __restrict__ meta_w,
                                                 float* __restrict__ out,
                                                 int k) {
    __shared__ __align__(16) float A[256 * 16];   // 16 KB
    __shared__ __align__(16) float H[1024 * 16];  // 64 KB
    const int tid = threadIdx.x;
    const int row0 = blockIdx.x * 16;
    const int b = row0 >> 12;       // / 4096
    const int t0 = row0 & 4095;
    const float wk = meta_w[b * K_TOP + k];

    const float* src = convbuf + ((size_t)b * T_LEN + t0) * C_DIM;
#pragma unroll
    for (int r = 0; r < 16; r++) A[tid * 16 + r] = src[(size_t)r * C_DIM + tid];
    __syncthreads();

    // phase 1: hidden = gelu(A^T @ W1 + b1); thread owns h = tid + 256*hj
    float acc[4][16];
#pragma unroll
    for (int hj = 0; hj < 4; hj++)
#pragma unroll
        for (int rr = 0; rr < 16; rr++) acc[hj][rr] = 0.0f;

    const float* W1p = W1 + tid;
    for (int ci = 0; ci < 256; ci++) {
        float af[16];
        *(float4*)&af[0]  = *(const float4*)&A[ci * 16 + 0];
        *(float4*)&af[4]  = *(const float4*)&A[ci * 16 + 4];
        *(float4*)&af[8]  = *(const float4*)&A[ci * 16 + 8];
        *(float4*)&af[12] = *(const float4*)&A[ci * 16 + 12];
#pragma unroll
        for (int hj = 0; hj < 4; hj++) {
            float wv = W1p[(size_t)ci * 1024 + 256 * hj];
#pragma unroll
            for (int rr = 0; rr < 16; rr++) acc[hj][rr] += af[rr] * wv;
        }
    }
#pragma unroll
    for (int hj = 0; hj < 4; hj++) {
        int h = tid + 256 * hj;
        float bb = b1[h];
#pragma unroll
        for (int rr = 0; rr < 16; rr++) H[h * 16 + rr] = gelu_exact(acc[hj][rr] + bb);
    }
    __syncthreads();

    // phase 2: out_c = H^T @ W2 + b2 ; thread owns c_out = tid
    float acc2[16];
#pragma unroll
    for (int rr = 0; rr < 16; rr++) acc2[rr] = 0.0f;
    const float* W2p = W2 + tid;
    for (int hi = 0; hi < 1024; hi++) {
        float hf[16];
        *(float4*)&hf[0]  = *(const float4*)&H[hi * 16 + 0];
        *(float4*)&hf[4]  = *(const float4*)&H[hi * 16 + 4];
        *(float4*)&hf[8]  = *(const float4*)&H[hi * 16 + 8];
        *(float4*)&hf[12] = *(const float4*)&H[hi * 16 + 12];
        float wv = W2p[(size_t)hi * C_DIM];
#pragma unroll
        for (int rr = 0; rr < 16; rr++) acc2[rr] += hf[rr] * wv;
    }

    const float bb2 = b2[tid];
    float* op = out + ((size_t)b * T_LEN + t0) * C_DIM + tid;
#pragma unroll
    for (int rr = 0; rr < 16; rr++) op[(size_t)rr * C_DIM] += wk * (acc2[rr] + bb2);
}

// ------------------------------------------------------------------
extern "C" void kernel_launch(void* const* d_in, const int* in_sizes, int n_in,
                              void* d_out, int out_size, void* d_ws, size_t ws_size,
                              hipStream_t stream) {
    const float* x  = (const float*)d_in[0];
    const float* Wc = (const float*)d_in[1];
    const float* bc = (const float*)d_in[2];
    const float* W1 = (const float*)d_in[3];
    const float* b1 = (const float*)d_in[4];
    const float* W2 = (const float*)d_in[5];
    const float* b2 = (const float*)d_in[6];
    float* out = (float*)d_out;

    // workspace carve (all fp32):
    float* mags = (float*)d_ws;                                    // 8*256*2048   = 16 MB
    float* amps = mags + (size_t)B_DIM * C_DIM * 2048;             // 8*2048
    int* meta_p = (int*)(amps + B_DIM * 2048);                     // 32 ints
    float* meta_w = (float*)(meta_p + B_DIM * K_TOP);              // 32 floats
    float* convbuf = meta_w + B_DIM * K_TOP;                       // 8*4096*256   = 33.5 MB

    // 1. out = x
    copy_x_kernel<<<dim3((B_DIM * T_LEN * C_DIM / 4) / 256), 256, 0, stream>>>(
        (const float4*)x, (float4*)out);

    // 2. FFT magnitudes per (b,c)
    fft_mag_kernel<<<dim3(B_DIM * C_DIM), 256, 0, stream>>>(x, mags);

    // 3. channel-mean -> amps[b][2048]
    reduce_amps_kernel<<<dim3(2048 / 256, B_DIM), 256, 0, stream>>>(mags, amps);

    // 4. top-4 + periods + softmax weights
    topk_kernel<<<dim3(B_DIM), 256, 0, stream>>>(amps, meta_p, meta_w);

    // 5. per-k: fold+conv+gelu+unfold, then FF accumulate into out
    for (int k = 0; k < K_TOP; k++) {
        conv_kernel<<<dim3(T_LEN / 8, B_DIM), 256, 0, stream>>>(x, Wc, bc, meta_p, convbuf, k);
        ff_kernel<<<dim3(B_DIM * T_LEN / 16), 256, 0, stream>>>(convbuf, W1, b1, W2, b2,
                                                                meta_w, out, k);
    }
}

// Round 4
// 799.603 us; speedup vs baseline: 6.8379x; 6.8379x over previous
//
#include <hip/hip_runtime.h>
#include <cstdint>
#include <cstddef>

#define T_LEN 4096
#define C_DIM 256
#define B_DIM 8
#define K_TOP 4

typedef __attribute__((ext_vector_type(8))) short bf16x8;
typedef __attribute__((ext_vector_type(4))) float f32x4;

__device__ __forceinline__ float gelu_exact(float x) {
    return 0.5f * x * (1.0f + erff(x * 0.70710678118654752f));
}

__device__ __forceinline__ unsigned short f2bf(float f) {
    uint32_t u = __float_as_uint(f);
    uint32_t r = (u + 0x7fffu + ((u >> 16) & 1u)) >> 16;
    return (unsigned short)r;
}

typedef __attribute__((address_space(3))) uint32_t lds_u32_t;
typedef __attribute__((address_space(1))) const uint32_t gbl_u32_t;

__device__ __forceinline__ void lds_load16(const void* g, void* l) {
    __builtin_amdgcn_global_load_lds((gbl_u32_t*)g, (lds_u32_t*)l, 16, 0, 0);
}

// ------------------------------------------------------------------
// out = x   (fp32, float4 vectorized)
// ------------------------------------------------------------------
__global__ __launch_bounds__(256) void copy_x_kernel(const float4* __restrict__ x,
                                                     float4* __restrict__ out) {
    size_t i = (size_t)blockIdx.x * 256 + threadIdx.x;
    out[i] = x[i];
}

// ------------------------------------------------------------------
// x fp32 -> bf16 (vectorized), plus zero the 512B zero-page
// ------------------------------------------------------------------
__global__ __launch_bounds__(256) void cvt_x_kernel(const float4* __restrict__ x,
                                                    ushort4* __restrict__ xbf,
                                                    unsigned short* __restrict__ zbuf) {
    size_t i = (size_t)blockIdx.x * 256 + threadIdx.x;  // over B*T*C/4
    float4 v = x[i];
    ushort4 o;
    o.x = f2bf(v.x); o.y = f2bf(v.y); o.z = f2bf(v.z); o.w = f2bf(v.w);
    xbf[i] = o;
    if (blockIdx.x == 0 && threadIdx.x < 256) zbuf[threadIdx.x] = 0;
}

// ------------------------------------------------------------------
// fp32 [R][C] -> bf16 transposed [C][R]
// ------------------------------------------------------------------
__global__ __launch_bounds__(256) void transpose_cvt_kernel(const float* __restrict__ src,
                                                            unsigned short* __restrict__ dst,
                                                            int R, int C) {
    __shared__ float t[32][33];
    const int c0 = blockIdx.x * 32, r0 = blockIdx.y * 32;
    const int lx = threadIdx.x & 31, ly = threadIdx.x >> 5;
    for (int rr = ly; rr < 32; rr += 8) {
        int r = r0 + rr, c = c0 + lx;
        t[rr][lx] = (r < R && c < C) ? src[(size_t)r * C + c] : 0.0f;
    }
    __syncthreads();
    for (int rr = ly; rr < 32; rr += 8) {
        int c = c0 + rr, r = r0 + lx;
        if (r < R && c < C) dst[(size_t)c * R + r] = f2bf(t[lx][rr]);
    }
}

// ------------------------------------------------------------------
// Per-(b,c) 4096-pt radix-2 DIT FFT in LDS; write |X_f| for f=1..2048
// ------------------------------------------------------------------
__global__ __launch_bounds__(256) void fft_mag_kernel(const float* __restrict__ x,
                                                      float* __restrict__ mags) {
    const int bx = blockIdx.x;
    const int b = bx >> 8;
    const int c = bx & 255;
    const int tid = threadIdx.x;

    __shared__ __align__(16) float re[4096];
    __shared__ __align__(16) float im[4096];
    __shared__ __align__(16) float twr[2048];
    __shared__ __align__(16) float twi[2048];

    for (int u = tid; u < 2048; u += 256) {
        float ang = -6.283185307179586f * (float)u / 4096.0f;
        float s, co;
        sincosf(ang, &s, &co);
        twr[u] = co;
        twi[u] = s;
    }
    const float* xp = x + (size_t)b * T_LEN * C_DIM + c;
    for (int e = tid; e < 4096; e += 256) {
        int r = (int)(__brev((unsigned)e) >> 20);
        re[r] = xp[(size_t)e * C_DIM];
        im[e] = 0.0f;
    }
    __syncthreads();

    for (int s = 1; s <= 12; s++) {
        const int half = 1 << (s - 1);
        const int shift = 12 - s;
        for (int j = tid; j < 2048; j += 256) {
            int p = j & (half - 1);
            int g = j >> (s - 1);
            int i1 = (g << s) + p;
            int i2 = i1 + half;
            float wr = twr[p << shift];
            float wi = twi[p << shift];
            float r2 = re[i2], q2 = im[i2];
            float tr = wr * r2 - wi * q2;
            float ti = wr * q2 + wi * r2;
            float r1 = re[i1], q1 = im[i1];
            re[i2] = r1 - tr;
            im[i2] = q1 - ti;
            re[i1] = r1 + tr;
            im[i1] = q1 + ti;
        }
        __syncthreads();
    }

    float* mp = mags + ((size_t)(b * C_DIM + c)) * 2048;
    for (int u = tid; u < 2048; u += 256) {
        int f = u + 1;
        mp[u] = sqrtf(re[f] * re[f] + im[f] * im[f]);
    }
}

// ------------------------------------------------------------------
// amps[b][u] = mean over c of mags[b][c][u]
// ------------------------------------------------------------------
__global__ __launch_bounds__(256) void reduce_amps_kernel(const float* __restrict__ mags,
                                                          float* __restrict__ amps) {
    const int b = blockIdx.y;
    const int u = blockIdx.x * 256 + threadIdx.x;
    const float* mp = mags + (size_t)b * C_DIM * 2048 + u;
    float s = 0.0f;
    for (int c = 0; c < C_DIM; c++) s += mp[(size_t)c * 2048];
    amps[b * 2048 + u] = s * (1.0f / (float)C_DIM);
}

// ------------------------------------------------------------------
// Per-batch top-4, periods, softmax weights
// ------------------------------------------------------------------
__global__ __launch_bounds__(256) void topk_kernel(const float* __restrict__ amps,
                                                   int* __restrict__ meta_p,
                                                   float* __restrict__ meta_w) {
    const int b = blockIdx.x;
    const int tid = threadIdx.x;
    __shared__ float v[2048];
    __shared__ float rv[256];
    __shared__ int ri[256];
    __shared__ float topv[K_TOP];
    __shared__ int topi[K_TOP];

    for (int u = tid; u < 2048; u += 256) v[u] = amps[b * 2048 + u];

    for (int k = 0; k < K_TOP; k++) {
        __syncthreads();
        float bv = -1e30f;
        int bi = 2048;
        for (int u = tid; u < 2048; u += 256) {
            float val = v[u];
            if (val > bv) { bv = val; bi = u; }
        }
        rv[tid] = bv;
        ri[tid] = bi;
        __syncthreads();
        for (int s = 128; s > 0; s >>= 1) {
            if (tid < s) {
                float ov = rv[tid + s];
                int oi = ri[tid + s];
                if (ov > rv[tid] || (ov == rv[tid] && oi < ri[tid])) {
                    rv[tid] = ov;
                    ri[tid] = oi;
                }
            }
            __syncthreads();
        }
        if (tid == 0) {
            topv[k] = rv[0];
            topi[k] = ri[0];
            v[ri[0]] = -1e30f;
        }
    }
    __syncthreads();
    if (tid == 0) {
        float mx = topv[0];
        for (int k = 1; k < K_TOP; k++) mx = fmaxf(mx, topv[k]);
        float e[K_TOP], se = 0.0f;
        for (int k = 0; k < K_TOP; k++) { e[k] = expf(topv[k] - mx); se += e[k]; }
        for (int k = 0; k < K_TOP; k++) {
            int idx = topi[k];
            int d = (idx >= 1) ? idx : 1;
            int p = T_LEN / d;
            if (p < 1) p = 1;
            meta_p[b * K_TOP + k] = p;
            meta_w[b * K_TOP + k] = e[k] / se;
        }
    }
}

// ------------------------------------------------------------------
// Conv as MFMA GEMM: [4096 x 2304] @ [2304 x 256] per (b,k).
// K-tile of 32 lies inside one q (2304 = 9*256, 32|256), so the A-stage
// is a row-shifted masked load of xbf; invalid rows load from the zero
// page (per-lane global src, linear LDS dest).  m97 structure: 128x128
// tile, BK=32, 4 waves, 2-barrier loop, global_load_lds width 16.
// Epilogue: gelu(acc + bc) -> convbuf bf16 [b*4096+t][256].
// ------------------------------------------------------------------
__global__ __launch_bounds__(256) void conv_mfma_kernel(const unsigned short* __restrict__ xbf,
                                                        const unsigned short* __restrict__ WcT,
                                                        const float* __restrict__ bc,
                                                        const int* __restrict__ meta_p,
                                                        const unsigned short* __restrict__ zbuf,
                                                        unsigned short* __restrict__ convbuf,
                                                        int k) {
    const int b = blockIdx.y;
    const int n = meta_p[b * K_TOP + k];
    const int tile_n = blockIdx.x & 1;
    const int tile_m = blockIdx.x >> 1;
    const int row0 = tile_m * 128, c0 = tile_n * 128;
    const int tid = threadIdx.x, w = tid >> 6, lane = tid & 63;
    const int wm = w >> 1, wn = w & 1;

    __shared__ __align__(16) unsigned short Al[128 * 32];
    __shared__ __align__(16) unsigned short Bl[128 * 32];

    // fold coords for my two staged rows (fixed across K-loop)
    int ti[2], tj[2];
#pragma unroll
    for (int s = 0; s < 2; s++) {
        int t = row0 + s * 64 + (tid >> 2);
        int ii = t / n;
        ti[s] = ii;
        tj[s] = t - ii * n;
    }
    const unsigned short* xb = xbf + (size_t)b * T_LEN * C_DIM;

    f32x4 acc[4][4];
#pragma unroll
    for (int m = 0; m < 4; m++)
#pragma unroll
        for (int nn = 0; nn < 4; nn++) acc[m][nn] = (f32x4){0.f, 0.f, 0.f, 0.f};

    for (int ks = 0; ks < 72; ks++) {
        const int kk = ks * 32;
        const int q = kk >> 8;
        const int di = q / 3 - 1, dj = q % 3 - 1;
        const int cib = (kk & 255) + (tid & 3) * 8;
        __syncthreads();
#pragma unroll
        for (int s = 0; s < 2; s++) {
            int ii = ti[s] + di, jj = tj[s] + dj;
            int tp = ii * n + jj;
            bool ok = (jj >= 0) && (jj < n) && (ii >= 0) && (tp < T_LEN);
            const unsigned short* srcA = ok ? (xb + (size_t)tp * C_DIM + cib) : zbuf;
            lds_load16(srcA, &Al[(s * 4 + w) * 512]);
            const unsigned short* srcB =
                WcT + (size_t)(c0 + s * 64 + (tid >> 2)) * 2304 + kk + (tid & 3) * 8;
            lds_load16(srcB, &Bl[(s * 4 + w) * 512]);
        }
        __syncthreads();

        bf16x8 af[4], bfr[4];
#pragma unroll
        for (int m = 0; m < 4; m++)
            af[m] = *(const bf16x8*)&Al[(wm * 64 + m * 16 + (lane & 15)) * 32 + (lane >> 4) * 8];
#pragma unroll
        for (int nn = 0; nn < 4; nn++)
            bfr[nn] = *(const bf16x8*)&Bl[(wn * 64 + nn * 16 + (lane & 15)) * 32 + (lane >> 4) * 8];
#pragma unroll
        for (int m = 0; m < 4; m++)
#pragma unroll
            for (int nn = 0; nn < 4; nn++)
                acc[m][nn] = __builtin_amdgcn_mfma_f32_16x16x32_bf16(af[m], bfr[nn], acc[m][nn], 0, 0, 0);
    }

    unsigned short* ob = convbuf + (size_t)b * T_LEN * C_DIM;
#pragma unroll
    for (int nn = 0; nn < 4; nn++) {
        int col = c0 + wn * 64 + nn * 16 + (lane & 15);
        float bs = bc[col];
#pragma unroll
        for (int m = 0; m < 4; m++) {
            int rbase = row0 + wm * 64 + m * 16 + (lane >> 4) * 4;
#pragma unroll
            for (int r = 0; r < 4; r++) {
                float v = acc[m][nn][r] + bs;
                ob[(size_t)(rbase + r) * C_DIM + col] = f2bf(gelu_exact(v));
            }
        }
    }
}

// ------------------------------------------------------------------
// FF GEMMs (m97 structure).  MODE 1: hidden = gelu(A@W1+b1) -> bf16.
// MODE 2: out[grow] += wk * (A@W2 + b2)  (fp32 RMW).
// A: bf16 row-major (lda elems).  BT: bf16 pre-transposed [N][K].
// ------------------------------------------------------------------
template <int MODE>
__global__ __launch_bounds__(256) void ff_gemm_kernel(const unsigned short* __restrict__ A,
                                                      int lda,
                                                      const unsigned short* __restrict__ BT,
                                                      int ldb, int ksteps, int ntiles,
                                                      const float* __restrict__ bias,
                                                      unsigned short* __restrict__ outb,
                                                      float* __restrict__ outf,
                                                      const float* __restrict__ meta_w,
                                                      int k, int grow0) {
    const int tile_n = blockIdx.x % ntiles;
    const int tile_m = blockIdx.x / ntiles;
    const int row0 = tile_m * 128, c0 = tile_n * 128;
    const int tid = threadIdx.x, w = tid >> 6, lane = tid & 63;
    const int wm = w >> 1, wn = w & 1;

    __shared__ __align__(16) unsigned short Al[128 * 32];
    __shared__ __align__(16) unsigned short Bl[128 * 32];

    f32x4 acc[4][4];
#pragma unroll
    for (int m = 0; m < 4; m++)
#pragma unroll
        for (int nn = 0; nn < 4; nn++) acc[m][nn] = (f32x4){0.f, 0.f, 0.f, 0.f};

    for (int ks = 0; ks < ksteps; ks++) {
        const int kk = ks * 32;
        __syncthreads();
#pragma unroll
        for (int s = 0; s < 2; s++) {
            const unsigned short* srcA =
                A + (size_t)(row0 + s * 64 + (tid >> 2)) * lda + kk + (tid & 3) * 8;
            lds_load16(srcA, &Al[(s * 4 + w) * 512]);
            const unsigned short* srcB =
                BT + (size_t)(c0 + s * 64 + (tid >> 2)) * ldb + kk + (tid & 3) * 8;
            lds_load16(srcB, &Bl[(s * 4 + w) * 512]);
        }
        __syncthreads();

        bf16x8 af[4], bfr[4];
#pragma unroll
        for (int m = 0; m < 4; m++)
            af[m] = *(const bf16x8*)&Al[(wm * 64 + m * 16 + (lane & 15)) * 32 + (lane >> 4) * 8];
#pragma unroll
        for (int nn = 0; nn < 4; nn++)
            bfr[nn] = *(const bf16x8*)&Bl[(wn * 64 + nn * 16 + (lane & 15)) * 32 + (lane >> 4) * 8];
#pragma unroll
        for (int m = 0; m < 4; m++)
#pragma unroll
            for (int nn = 0; nn < 4; nn++)
                acc[m][nn] = __builtin_amdgcn_mfma_f32_16x16x32_bf16(af[m], bfr[nn], acc[m][nn], 0, 0, 0);
    }

    if (MODE == 1) {
#pragma unroll
        for (int nn = 0; nn < 4; nn++) {
            int col = c0 + wn * 64 + nn * 16 + (lane & 15);
            float bs = bias[col];
#pragma unroll
            for (int m = 0; m < 4; m++) {
                int rbase = row0 + wm * 64 + m * 16 + (lane >> 4) * 4;
#pragma unroll
                for (int r = 0; r < 4; r++) {
                    float v = acc[m][nn][r] + bs;
                    outb[(size_t)(rbase + r) * 1024 + col] = f2bf(gelu_exact(v));
                }
            }
        }
    } else {
        const int bidx = (grow0 + row0) >> 12;  // tiles never cross a batch boundary
        const float wk = meta_w[bidx * K_TOP + k];
#pragma unroll
        for (int nn = 0; nn < 4; nn++) {
            int col = c0 + wn * 64 + nn * 16 + (lane & 15);
            float bs = bias[col];
#pragma unroll
            for (int m = 0; m < 4; m++) {
                int rbase = row0 + wm * 64 + m * 16 + (lane >> 4) * 4;
#pragma unroll
                for (int r = 0; r < 4; r++) {
                    size_t grow = (size_t)grow0 + rbase + r;
                    outf[grow * C_DIM + col] += wk * (acc[m][nn][r] + bs);
                }
            }
        }
    }
}

// ------------------------------------------------------------------
extern "C" void kernel_launch(void* const* d_in, const int* in_sizes, int n_in,
                              void* d_out, int out_size, void* d_ws, size_t ws_size,
                              hipStream_t stream) {
    const float* x  = (const float*)d_in[0];
    const float* Wc = (const float*)d_in[1];
    const float* bc = (const float*)d_in[2];
    const float* W1 = (const float*)d_in[3];
    const float* b1 = (const float*)d_in[4];
    const float* W2 = (const float*)d_in[5];
    const float* b2 = (const float*)d_in[6];
    float* out = (float*)d_out;

    // ---- workspace carve (256B aligned) ----
    uint8_t* ws = (uint8_t*)d_ws;
    size_t off = 0;
    auto alloc = [&](size_t bytes) {
        size_t o = off;
        off = (off + bytes + 255) & ~(size_t)255;
        return o;
    };
    // region0: mags (fp32, FFT phase) and convbuf (bf16, conv/FF phase) — same 16 MB
    size_t region0_off = alloc((size_t)B_DIM * C_DIM * 2048 * 4);
    float* mags = (float*)(ws + region0_off);
    unsigned short* convbuf = (unsigned short*)(ws + region0_off);  // 32768*256*2 == same size
    float* amps = (float*)(ws + alloc((size_t)B_DIM * 2048 * 4));
    int* meta_p = (int*)(ws + alloc(B_DIM * K_TOP * 4));
    float* meta_w = (float*)(ws + alloc(B_DIM * K_TOP * 4));
    unsigned short* xbf = (unsigned short*)(ws + alloc((size_t)B_DIM * T_LEN * C_DIM * 2));
    unsigned short* WcT = (unsigned short*)(ws + alloc((size_t)256 * 2304 * 2));
    unsigned short* W1T = (unsigned short*)(ws + alloc((size_t)1024 * 256 * 2));
    unsigned short* W2T = (unsigned short*)(ws + alloc((size_t)256 * 1024 * 2));
    unsigned short* zbuf = (unsigned short*)(ws + alloc(512));
    // hidden: whatever is left, chunked
    size_t avail = (ws_size > off) ? (ws_size - off) : 0;
    int chunk = (int)((avail / (1024 * 2)) / 128) * 128;
    const int ROWS = B_DIM * T_LEN;  // 32768
    if (chunk > ROWS) chunk = ROWS;
    if (chunk < 128) chunk = 128;  // (ws is known >= ~50MB; this never triggers)
    unsigned short* hidden = (unsigned short*)(ws + off);

    // 1. out = x
    copy_x_kernel<<<dim3((B_DIM * T_LEN * C_DIM / 4) / 256), 256, 0, stream>>>(
        (const float4*)x, (float4*)out);

    // 2. conversions: x -> bf16 (+zero page), weights -> transposed bf16
    cvt_x_kernel<<<dim3((B_DIM * T_LEN * C_DIM / 4) / 256), 256, 0, stream>>>(
        (const float4*)x, (ushort4*)xbf, zbuf);
    transpose_cvt_kernel<<<dim3(256 / 32, 2304 / 32), 256, 0, stream>>>(Wc, WcT, 2304, 256);
    transpose_cvt_kernel<<<dim3(1024 / 32, 256 / 32), 256, 0, stream>>>(W1, W1T, 256, 1024);
    transpose_cvt_kernel<<<dim3(256 / 32, 1024 / 32), 256, 0, stream>>>(W2, W2T, 1024, 256);

    // 3. FFT magnitudes, channel mean, top-4
    fft_mag_kernel<<<dim3(B_DIM * C_DIM), 256, 0, stream>>>(x, mags);
    reduce_amps_kernel<<<dim3(2048 / 256, B_DIM), 256, 0, stream>>>(mags, amps);
    topk_kernel<<<dim3(B_DIM), 256, 0, stream>>>(amps, meta_p, meta_w);

    // 4. per-k: conv GEMM -> convbuf, then FF GEMMs (chunked hidden)
    for (int k = 0; k < K_TOP; k++) {
        conv_mfma_kernel<<<dim3(64, B_DIM), 256, 0, stream>>>(xbf, WcT, bc, meta_p, zbuf,
                                                              convbuf, k);
        for (int r0 = 0; r0 < ROWS; r0 += chunk) {
            int rows = ROWS - r0;
            if (rows > chunk) rows = chunk;
            ff_gemm_kernel<1><<<dim3((rows / 128) * 8), 256, 0, stream>>>(
                convbuf + (size_t)r0 * C_DIM, C_DIM, W1T, 256, 8, 8, b1, hidden, nullptr,
                meta_w, k, 0);
            ff_gemm_kernel<2><<<dim3((rows / 128) * 2), 256, 0, stream>>>(
                hidden, 1024, W2T, 1024, 32, 2, b2, nullptr, out, meta_w, k, r0);
        }
    }
}

// Round 5
// 700.708 us; speedup vs baseline: 7.8029x; 1.1411x over previous
//
#include <hip/hip_runtime.h>
#include <cstdint>
#include <cstddef>

#define T_LEN 4096
#define C_DIM 256
#define B_DIM 8
#define K_TOP 4

typedef __attribute__((ext_vector_type(8))) short bf16x8;
typedef __attribute__((ext_vector_type(4))) float f32x4;

__device__ __forceinline__ float gelu_exact(float x) {
    return 0.5f * x * (1.0f + erff(x * 0.70710678118654752f));
}

__device__ __forceinline__ unsigned short f2bf(float f) {
    uint32_t u = __float_as_uint(f);
    uint32_t r = (u + 0x7fffu + ((u >> 16) & 1u)) >> 16;
    return (unsigned short)r;
}

typedef __attribute__((address_space(3))) uint32_t lds_u32_t;
typedef __attribute__((address_space(1))) const uint32_t gbl_u32_t;

__device__ __forceinline__ void lds_load16(const void* g, void* l) {
    __builtin_amdgcn_global_load_lds((gbl_u32_t*)g, (lds_u32_t*)l, 16, 0, 0);
}

// padded LDS index: +1 float per 32 -> breaks power-of-2 bank aliasing
#define FPAD(i) ((i) + ((i) >> 5))

// ------------------------------------------------------------------
// out = x  AND  xbf = bf16(x)  (single read of x), plus zero page
// ------------------------------------------------------------------
__global__ __launch_bounds__(256) void cvt_x_kernel(const float4* __restrict__ x,
                                                    float4* __restrict__ out,
                                                    ushort4* __restrict__ xbf,
                                                    unsigned short* __restrict__ zbuf) {
    size_t i = (size_t)blockIdx.x * 256 + threadIdx.x;  // over B*T*C/4
    float4 v = x[i];
    out[i] = v;
    ushort4 o;
    o.x = f2bf(v.x); o.y = f2bf(v.y); o.z = f2bf(v.z); o.w = f2bf(v.w);
    xbf[i] = o;
    if (blockIdx.x == 0 && threadIdx.x < 256) zbuf[threadIdx.x] = 0;
}

// ------------------------------------------------------------------
// fp32 [R][C] -> bf16 transposed [C][R]   (weights)
// ------------------------------------------------------------------
__global__ __launch_bounds__(256) void transpose_cvt_kernel(const float* __restrict__ src,
                                                            unsigned short* __restrict__ dst,
                                                            int R, int C) {
    __shared__ float t[32][33];
    const int c0 = blockIdx.x * 32, r0 = blockIdx.y * 32;
    const int lx = threadIdx.x & 31, ly = threadIdx.x >> 5;
    for (int rr = ly; rr < 32; rr += 8) {
        int r = r0 + rr, c = c0 + lx;
        t[rr][lx] = (r < R && c < C) ? src[(size_t)r * C + c] : 0.0f;
    }
    __syncthreads();
    for (int rr = ly; rr < 32; rr += 8) {
        int c = c0 + rr, r = r0 + lx;
        if (r < R && c < C) dst[(size_t)c * R + r] = f2bf(t[lx][rr]);
    }
}

// ------------------------------------------------------------------
// fp32 x[b][t][c] -> xT[b][c][t]  (coalesced both sides via LDS tile)
// ------------------------------------------------------------------
__global__ __launch_bounds__(256) void transpose_x_kernel(const float* __restrict__ x,
                                                          float* __restrict__ xT) {
    __shared__ float tile[32][33];
    const int b = blockIdx.z;
    const int t0 = blockIdx.x * 32, c0 = blockIdx.y * 32;
    const int lx = threadIdx.x & 31, ly = threadIdx.x >> 5;
    const float* xp = x + (size_t)b * T_LEN * C_DIM;
    float* op = xT + (size_t)b * C_DIM * T_LEN;
    for (int rr = ly; rr < 32; rr += 8)
        tile[rr][lx] = xp[(size_t)(t0 + rr) * C_DIM + c0 + lx];
    __syncthreads();
    for (int rr = ly; rr < 32; rr += 8)
        op[(size_t)(c0 + rr) * T_LEN + t0 + lx] = tile[lx][rr];
}

// ------------------------------------------------------------------
// Per-(b,c) 4096-pt FFT, fused radix-2 stage-pairs (6 LDS passes),
// pad-32 LDS indexing.  transposed=1: read contiguous row from xT;
// else strided from x (fallback when ws too small for xT).
// Writes |X_f|, f=1..2048 -> mags[b][c][u].
// ------------------------------------------------------------------
__global__ __launch_bounds__(256) void fft_mag_kernel(const float* __restrict__ src,
                                                      float* __restrict__ mags,
                                                      int transposed) {
    const int bx = blockIdx.x;
    const int b = bx >> 8;
    const int c = bx & 255;
    const int tid = threadIdx.x;

    __shared__ __align__(16) float re[4224];   // 4096 + 128 pad
    __shared__ __align__(16) float im[4224];
    __shared__ __align__(16) float twr[2048];
    __shared__ __align__(16) float twi[2048];

    for (int u = tid; u < 2048; u += 256) {
        float ang = -6.283185307179586f * (float)u / 4096.0f;
        float s, co;
        sincosf(ang, &s, &co);
        twr[u] = co;
        twi[u] = s;
    }
    for (int i = tid; i < 4224; i += 256) im[i] = 0.0f;

    if (transposed) {
        const float4* row = (const float4*)(src + ((size_t)(b * C_DIM + c)) * T_LEN);
        for (int e4 = tid; e4 < 1024; e4 += 256) {
            float4 v = row[e4];
            int e = e4 * 4;
            re[FPAD((int)(__brev((unsigned)(e + 0)) >> 20))] = v.x;
            re[FPAD((int)(__brev((unsigned)(e + 1)) >> 20))] = v.y;
            re[FPAD((int)(__brev((unsigned)(e + 2)) >> 20))] = v.z;
            re[FPAD((int)(__brev((unsigned)(e + 3)) >> 20))] = v.w;
        }
    } else {
        const float* xp = src + (size_t)b * T_LEN * C_DIM + c;
        for (int e = tid; e < 4096; e += 256) {
            int r = (int)(__brev((unsigned)e) >> 20);
            re[FPAD(r)] = xp[(size_t)e * C_DIM];
        }
    }
    __syncthreads();

    // 6 fused passes; pass sp covers radix-2 stages s=2sp+1 and s+1.
    // W3 = tw[(p+h)<<(11-s)] = -i * W2  (tw[k+1024] = -i*tw[k]).
#pragma unroll
    for (int sp = 0; sp < 6; sp++) {
        const int h = 1 << (2 * sp);
        const int t1s = 11 - 2 * sp;  // 12 - s
        const int t2s = 10 - 2 * sp;  // 11 - s
        for (int j = tid; j < 1024; j += 256) {
            int p = j & (h - 1);
            int G = j >> (2 * sp);
            int base = G * 4 * h + p;
            int iA = FPAD(base), iB = FPAD(base + h);
            int iC = FPAD(base + 2 * h), iD = FPAD(base + 3 * h);
            float w1r = twr[p << t1s], w1i = twi[p << t1s];
            float w2r = twr[p << t2s], w2i = twi[p << t2s];
            float Ar = re[iA], Ai = im[iA], Br = re[iB], Bi = im[iB];
            float Cr = re[iC], Ci = im[iC], Dr = re[iD], Di = im[iD];
            // stage s
            float tBr = w1r * Br - w1i * Bi, tBi = w1r * Bi + w1i * Br;
            float tDr = w1r * Dr - w1i * Di, tDi = w1r * Di + w1i * Dr;
            float A1r = Ar + tBr, A1i = Ai + tBi;
            float B1r = Ar - tBr, B1i = Ai - tBi;
            float C1r = Cr + tDr, C1i = Ci + tDi;
            float D1r = Cr - tDr, D1i = Ci - tDi;
            // stage s+1
            float tCr = w2r * C1r - w2i * C1i, tCi = w2r * C1i + w2i * C1r;
            float uDr = w2r * D1r - w2i * D1i, uDi = w2r * D1i + w2i * D1r;
            float vDr = uDi, vDi = -uDr;  // -i * (W2*D1)
            re[iA] = A1r + tCr; im[iA] = A1i + tCi;
            re[iC] = A1r - tCr; im[iC] = A1i - tCi;
            re[iB] = B1r + vDr; im[iB] = B1i + vDi;
            re[iD] = B1r - vDr; im[iD] = B1i - vDi;
        }
        __syncthreads();
    }

    float* mp = mags + ((size_t)(b * C_DIM + c)) * 2048;
    for (int u = tid; u < 2048; u += 256) {
        int f = FPAD(u + 1);
        mp[u] = sqrtf(re[f] * re[f] + im[f] * im[f]);
    }
}

// ------------------------------------------------------------------
// partial[b][cc][u] = sum over 32 channels of mags  (512 WGs)
// ------------------------------------------------------------------
__global__ __launch_bounds__(256) void reduce_amps_kernel(const float* __restrict__ mags,
                                                          float* __restrict__ partial) {
    const int b = blockIdx.z, cc = blockIdx.y;
    const int u = blockIdx.x * 256 + threadIdx.x;
    const float* mp = mags + ((size_t)b * C_DIM + cc * 32) * 2048 + u;
    float s = 0.0f;
    for (int c = 0; c < 32; c++) s += mp[(size_t)c * 2048];
    partial[((size_t)b * 8 + cc) * 2048 + u] = s;
}

// ------------------------------------------------------------------
// Per-batch top-4 (value desc, ties -> lower index), periods, softmax
// ------------------------------------------------------------------
__global__ __launch_bounds__(256) void topk_kernel(const float* __restrict__ partial,
                                                   int* __restrict__ meta_p,
                                                   float* __restrict__ meta_w) {
    const int b = blockIdx.x;
    const int tid = threadIdx.x;
    __shared__ float v[2048];
    __shared__ float rv[256];
    __shared__ int ri[256];
    __shared__ float topv[K_TOP];
    __shared__ int topi[K_TOP];

    for (int u = tid; u < 2048; u += 256) {
        float s = 0.0f;
        for (int cc = 0; cc < 8; cc++) s += partial[((size_t)b * 8 + cc) * 2048 + u];
        v[u] = s * (1.0f / (float)C_DIM);
    }

    for (int k = 0; k < K_TOP; k++) {
        __syncthreads();
        float bv = -1e30f;
        int bi = 2048;
        for (int u = tid; u < 2048; u += 256) {
            float val = v[u];
            if (val > bv) { bv = val; bi = u; }
        }
        rv[tid] = bv;
        ri[tid] = bi;
        __syncthreads();
        for (int s = 128; s > 0; s >>= 1) {
            if (tid < s) {
                float ov = rv[tid + s];
                int oi = ri[tid + s];
                if (ov > rv[tid] || (ov == rv[tid] && oi < ri[tid])) {
                    rv[tid] = ov;
                    ri[tid] = oi;
                }
            }
            __syncthreads();
        }
        if (tid == 0) {
            topv[k] = rv[0];
            topi[k] = ri[0];
            v[ri[0]] = -1e30f;
        }
    }
    __syncthreads();
    if (tid == 0) {
        float mx = topv[0];
        for (int k = 1; k < K_TOP; k++) mx = fmaxf(mx, topv[k]);
        float e[K_TOP], se = 0.0f;
        for (int k = 0; k < K_TOP; k++) { e[k] = expf(topv[k] - mx); se += e[k]; }
        for (int k = 0; k < K_TOP; k++) {
            int idx = topi[k];
            int d = (idx >= 1) ? idx : 1;
            int p = T_LEN / d;
            if (p < 1) p = 1;
            meta_p[b * K_TOP + k] = p;
            meta_w[b * K_TOP + k] = e[k] / se;
        }
    }
}

// ------------------------------------------------------------------
// Conv as MFMA GEMM: [4096 x 2304] @ [2304 x 256] per (b,k).
// q-hoisted: fold addresses + bounds select computed once per q (9x),
// inner 8 K-steps just advance by kc*32.  m97 structure otherwise.
// ------------------------------------------------------------------
__global__ __launch_bounds__(256) void conv_mfma_kernel(const unsigned short* __restrict__ xbf,
                                                        const unsigned short* __restrict__ WcT,
                                                        const float* __restrict__ bc,
                                                        const int* __restrict__ meta_p,
                                                        const unsigned short* __restrict__ zbuf,
                                                        unsigned short* __restrict__ convbuf,
                                                        int k) {
    const int b = blockIdx.y;
    const int n = meta_p[b * K_TOP + k];
    const int tile_n = blockIdx.x & 1;
    const int tile_m = blockIdx.x >> 1;
    const int row0 = tile_m * 128, c0 = tile_n * 128;
    const int tid = threadIdx.x, w = tid >> 6, lane = tid & 63;
    const int wm = w >> 1, wn = w & 1;

    __shared__ __align__(16) unsigned short Al[128 * 32];
    __shared__ __align__(16) unsigned short Bl[128 * 32];

    int ti[2], tj[2];
#pragma unroll
    for (int s = 0; s < 2; s++) {
        int t = row0 + s * 64 + (tid >> 2);
        int ii = t / n;
        ti[s] = ii;
        tj[s] = t - ii * n;
    }
    const unsigned short* xb = xbf + (size_t)b * T_LEN * C_DIM;
    const int lco = (tid & 3) * 8;  // lane column offset (elements)

    f32x4 acc[4][4];
#pragma unroll
    for (int m = 0; m < 4; m++)
#pragma unroll
        for (int nn = 0; nn < 4; nn++) acc[m][nn] = (f32x4){0.f, 0.f, 0.f, 0.f};

    for (int q = 0; q < 9; q++) {
        const int di = q / 3 - 1, dj = q % 3 - 1;
        const unsigned short* baseA[2];
        const unsigned short* baseB[2];
#pragma unroll
        for (int s = 0; s < 2; s++) {
            int ii = ti[s] + di, jj = tj[s] + dj;
            int tp = ii * n + jj;
            bool ok = (jj >= 0) && (jj < n) && (ii >= 0) && (tp < T_LEN);
            baseA[s] = ok ? (xb + (size_t)tp * C_DIM + lco) : (zbuf + lco);
            baseB[s] = WcT + (size_t)(c0 + s * 64 + (tid >> 2)) * 2304 + q * 256 + lco;
        }
        for (int kc = 0; kc < 8; kc++) {
            __syncthreads();
#pragma unroll
            for (int s = 0; s < 2; s++) {
                lds_load16(baseA[s] + kc * 32, &Al[(s * 4 + w) * 512]);
                lds_load16(baseB[s] + kc * 32, &Bl[(s * 4 + w) * 512]);
            }
            __syncthreads();

            bf16x8 af[4], bfr[4];
#pragma unroll
            for (int m = 0; m < 4; m++)
                af[m] = *(const bf16x8*)&Al[(wm * 64 + m * 16 + (lane & 15)) * 32 + (lane >> 4) * 8];
#pragma unroll
            for (int nn = 0; nn < 4; nn++)
                bfr[nn] = *(const bf16x8*)&Bl[(wn * 64 + nn * 16 + (lane & 15)) * 32 + (lane >> 4) * 8];
#pragma unroll
            for (int m = 0; m < 4; m++)
#pragma unroll
                for (int nn = 0; nn < 4; nn++)
                    acc[m][nn] = __builtin_amdgcn_mfma_f32_16x16x32_bf16(af[m], bfr[nn], acc[m][nn], 0, 0, 0);
        }
    }

    unsigned short* ob = convbuf + (size_t)b * T_LEN * C_DIM;
#pragma unroll
    for (int nn = 0; nn < 4; nn++) {
        int col = c0 + wn * 64 + nn * 16 + (lane & 15);
        float bs = bc[col];
#pragma unroll
        for (int m = 0; m < 4; m++) {
            int rbase = row0 + wm * 64 + m * 16 + (lane >> 4) * 4;
#pragma unroll
            for (int r = 0; r < 4; r++) {
                float v = acc[m][nn][r] + bs;
                ob[(size_t)(rbase + r) * C_DIM + col] = f2bf(gelu_exact(v));
            }
        }
    }
}

// ------------------------------------------------------------------
// FF GEMMs (m97 structure).  MODE 1: hidden = gelu(A@W1+b1) -> bf16.
// MODE 2: out[grow] += wk * (A@W2 + b2)  (fp32 RMW).
// ------------------------------------------------------------------
template <int MODE>
__global__ __launch_bounds__(256) void ff_gemm_kernel(const unsigned short* __restrict__ A,
                                                      int lda,
                                                      const unsigned short* __restrict__ BT,
                                                      int ldb, int ksteps, int ntiles,
                                                      const float* __restrict__ bias,
                                                      unsigned short* __restrict__ outb,
                                                      float* __restrict__ outf,
                                                      const float* __restrict__ meta_w,
                                                      int k, int grow0) {
    const int tile_n = blockIdx.x % ntiles;
    const int tile_m = blockIdx.x / ntiles;
    const int row0 = tile_m * 128, c0 = tile_n * 128;
    const int tid = threadIdx.x, w = tid >> 6, lane = tid & 63;
    const int wm = w >> 1, wn = w & 1;

    __shared__ __align__(16) unsigned short Al[128 * 32];
    __shared__ __align__(16) unsigned short Bl[128 * 32];

    f32x4 acc[4][4];
#pragma unroll
    for (int m = 0; m < 4; m++)
#pragma unroll
        for (int nn = 0; nn < 4; nn++) acc[m][nn] = (f32x4){0.f, 0.f, 0.f, 0.f};

    for (int ks = 0; ks < ksteps; ks++) {
        const int kk = ks * 32;
        __syncthreads();
#pragma unroll
        for (int s = 0; s < 2; s++) {
            const unsigned short* srcA =
                A + (size_t)(row0 + s * 64 + (tid >> 2)) * lda + kk + (tid & 3) * 8;
            lds_load16(srcA, &Al[(s * 4 + w) * 512]);
            const unsigned short* srcB =
                BT + (size_t)(c0 + s * 64 + (tid >> 2)) * ldb + kk + (tid & 3) * 8;
            lds_load16(srcB, &Bl[(s * 4 + w) * 512]);
        }
        __syncthreads();

        bf16x8 af[4], bfr[4];
#pragma unroll
        for (int m = 0; m < 4; m++)
            af[m] = *(const bf16x8*)&Al[(wm * 64 + m * 16 + (lane & 15)) * 32 + (lane >> 4) * 8];
#pragma unroll
        for (int nn = 0; nn < 4; nn++)
            bfr[nn] = *(const bf16x8*)&Bl[(wn * 64 + nn * 16 + (lane & 15)) * 32 + (lane >> 4) * 8];
#pragma unroll
        for (int m = 0; m < 4; m++)
#pragma unroll
            for (int nn = 0; nn < 4; nn++)
                acc[m][nn] = __builtin_amdgcn_mfma_f32_16x16x32_bf16(af[m], bfr[nn], acc[m][nn], 0, 0, 0);
    }

    if (MODE == 1) {
#pragma unroll
        for (int nn = 0; nn < 4; nn++) {
            int col = c0 + wn * 64 + nn * 16 + (lane & 15);
            float bs = bias[col];
#pragma unroll
            for (int m = 0; m < 4; m++) {
                int rbase = row0 + wm * 64 + m * 16 + (lane >> 4) * 4;
#pragma unroll
                for (int r = 0; r < 4; r++) {
                    float v = acc[m][nn][r] + bs;
                    outb[(size_t)(rbase + r) * 1024 + col] = f2bf(gelu_exact(v));
                }
            }
        }
    } else {
        const int bidx = (grow0 + row0) >> 12;
        const float wk = meta_w[bidx * K_TOP + k];
#pragma unroll
        for (int nn = 0; nn < 4; nn++) {
            int col = c0 + wn * 64 + nn * 16 + (lane & 15);
            float bs = bias[col];
#pragma unroll
            for (int m = 0; m < 4; m++) {
                int rbase = row0 + wm * 64 + m * 16 + (lane >> 4) * 4;
#pragma unroll
                for (int r = 0; r < 4; r++) {
                    size_t grow = (size_t)grow0 + rbase + r;
                    outf[grow * C_DIM + col] += wk * (acc[m][nn][r] + bs);
                }
            }
        }
    }
}

// ------------------------------------------------------------------
extern "C" void kernel_launch(void* const* d_in, const int* in_sizes, int n_in,
                              void* d_out, int out_size, void* d_ws, size_t ws_size,
                              hipStream_t stream) {
    const float* x  = (const float*)d_in[0];
    const float* Wc = (const float*)d_in[1];
    const float* bc = (const float*)d_in[2];
    const float* W1 = (const float*)d_in[3];
    const float* b1 = (const float*)d_in[4];
    const float* W2 = (const float*)d_in[5];
    const float* b2 = (const float*)d_in[6];
    float* out = (float*)d_out;

    // ---- workspace carve (256B aligned) ----
    uint8_t* ws = (uint8_t*)d_ws;
    size_t off = 0;
    auto alloc = [&](size_t bytes) {
        size_t o = off;
        off = (off + bytes + 255) & ~(size_t)255;
        return o;
    };
    // region0: mags (fp32, FFT phase) aliases convbuf (bf16, conv/FF phase)
    size_t region0_off = alloc((size_t)B_DIM * C_DIM * 2048 * 4);
    float* mags = (float*)(ws + region0_off);
    unsigned short* convbuf = (unsigned short*)(ws + region0_off);
    float* partial = (float*)(ws + alloc((size_t)B_DIM * 8 * 2048 * 4));
    int* meta_p = (int*)(ws + alloc(B_DIM * K_TOP * 4));
    float* meta_w = (float*)(ws + alloc(B_DIM * K_TOP * 4));
    unsigned short* xbf = (unsigned short*)(ws + alloc((size_t)B_DIM * T_LEN * C_DIM * 2));
    unsigned short* WcT = (unsigned short*)(ws + alloc((size_t)256 * 2304 * 2));
    unsigned short* W1T = (unsigned short*)(ws + alloc((size_t)1024 * 256 * 2));
    unsigned short* W2T = (unsigned short*)(ws + alloc((size_t)256 * 1024 * 2));
    unsigned short* zbuf = (unsigned short*)(ws + alloc(512));

    // tail region: xT (fp32, FFT phase) aliases hidden (bf16, FF phase)
    size_t tail_avail = (ws_size > off) ? (ws_size - off) : 0;
    const size_t xT_bytes = (size_t)B_DIM * T_LEN * C_DIM * 4;
    const int use_xT = (tail_avail >= xT_bytes) ? 1 : 0;
    float* xT = (float*)(ws + off);
    unsigned short* hidden = (unsigned short*)(ws + off);
    int chunk = (int)((tail_avail / (1024 * 2)) / 128) * 128;
    const int ROWS = B_DIM * T_LEN;  // 32768
    if (chunk > ROWS) chunk = ROWS;
    if (chunk < 128) chunk = 128;

    // 1. out = x ; xbf = bf16(x) ; zero page
    cvt_x_kernel<<<dim3((B_DIM * T_LEN * C_DIM / 4) / 256), 256, 0, stream>>>(
        (const float4*)x, (float4*)out, (ushort4*)xbf, zbuf);

    // 2. weight transposes -> bf16
    transpose_cvt_kernel<<<dim3(256 / 32, 2304 / 32), 256, 0, stream>>>(Wc, WcT, 2304, 256);
    transpose_cvt_kernel<<<dim3(1024 / 32, 256 / 32), 256, 0, stream>>>(W1, W1T, 256, 1024);
    transpose_cvt_kernel<<<dim3(256 / 32, 1024 / 32), 256, 0, stream>>>(W2, W2T, 1024, 256);

    // 3. FFT magnitudes (coalesced via xT when ws allows), reduce, top-4
    if (use_xT) {
        transpose_x_kernel<<<dim3(T_LEN / 32, C_DIM / 32, B_DIM), 256, 0, stream>>>(x, xT);
        fft_mag_kernel<<<dim3(B_DIM * C_DIM), 256, 0, stream>>>(xT, mags, 1);
    } else {
        fft_mag_kernel<<<dim3(B_DIM * C_DIM), 256, 0, stream>>>(x, mags, 0);
    }
    reduce_amps_kernel<<<dim3(2048 / 256, 8, B_DIM), 256, 0, stream>>>(mags, partial);
    topk_kernel<<<dim3(B_DIM), 256, 0, stream>>>(partial, meta_p, meta_w);

    // 4. per-k: conv GEMM -> convbuf, then FF GEMMs (chunked hidden)
    for (int k = 0; k < K_TOP; k++) {
        conv_mfma_kernel<<<dim3(64, B_DIM), 256, 0, stream>>>(xbf, WcT, bc, meta_p, zbuf,
                                                              convbuf, k);
        for (int r0 = 0; r0 < ROWS; r0 += chunk) {
            int rows = ROWS - r0;
            if (rows > chunk) rows = chunk;
            ff_gemm_kernel<1><<<dim3((rows / 128) * 8), 256, 0, stream>>>(
                convbuf + (size_t)r0 * C_DIM, C_DIM, W1T, 256, 8, 8, b1, hidden, nullptr,
                meta_w, k, 0);
            ff_gemm_kernel<2><<<dim3((rows / 128) * 2), 256, 0, stream>>>(
                hidden, 1024, W2T, 1024, 32, 2, b2, nullptr, out, meta_w, k, r0);
        }
    }
}

// Round 6
// 527.177 us; speedup vs baseline: 10.3714x; 1.3292x over previous
//
#include <hip/hip_runtime.h>
#include <cstdint>
#include <cstddef>

#define T_LEN 4096
#define C_DIM 256
#define B_DIM 8
#define K_TOP 4

typedef __attribute__((ext_vector_type(8))) short bf16x8;
typedef __attribute__((ext_vector_type(4))) float f32x4;

__device__ __forceinline__ float gelu_exact(float x) {
    return 0.5f * x * (1.0f + erff(x * 0.70710678118654752f));
}

__device__ __forceinline__ unsigned short f2bf(float f) {
    uint32_t u = __float_as_uint(f);
    uint32_t r = (u + 0x7fffu + ((u >> 16) & 1u)) >> 16;
    return (unsigned short)r;
}

typedef __attribute__((address_space(3))) uint32_t lds_u32_t;
typedef __attribute__((address_space(1))) const uint32_t gbl_u32_t;

__device__ __forceinline__ void lds_load16(const void* g, void* l) {
    __builtin_amdgcn_global_load_lds((gbl_u32_t*)g, (lds_u32_t*)l, 16, 0, 0);
}

// padded LDS index for FFT: +1 float per 32
#define FPAD(i) ((i) + ((i) >> 5))

// ------------------------------------------------------------------
// out = x  AND  xbf = bf16(x)  (single read of x), plus zero page
// ------------------------------------------------------------------
__global__ __launch_bounds__(256) void cvt_x_kernel(const float4* __restrict__ x,
                                                    float4* __restrict__ out,
                                                    ushort4* __restrict__ xbf,
                                                    unsigned short* __restrict__ zbuf) {
    size_t i = (size_t)blockIdx.x * 256 + threadIdx.x;
    float4 v = x[i];
    out[i] = v;
    ushort4 o;
    o.x = f2bf(v.x); o.y = f2bf(v.y); o.z = f2bf(v.z); o.w = f2bf(v.w);
    xbf[i] = o;
    if (blockIdx.x == 0 && threadIdx.x < 256) zbuf[threadIdx.x] = 0;
}

// ------------------------------------------------------------------
// fp32 [R][C] -> bf16 transposed [C][R]   (conv weights)
// ------------------------------------------------------------------
__global__ __launch_bounds__(256) void transpose_cvt_kernel(const float* __restrict__ src,
                                                            unsigned short* __restrict__ dst,
                                                            int R, int C) {
    __shared__ float t[32][33];
    const int c0 = blockIdx.x * 32, r0 = blockIdx.y * 32;
    const int lx = threadIdx.x & 31, ly = threadIdx.x >> 5;
    for (int rr = ly; rr < 32; rr += 8) {
        int r = r0 + rr, c = c0 + lx;
        t[rr][lx] = (r < R && c < C) ? src[(size_t)r * C + c] : 0.0f;
    }
    __syncthreads();
    for (int rr = ly; rr < 32; rr += 8) {
        int c = c0 + rr, r = r0 + lx;
        if (r < R && c < C) dst[(size_t)c * R + r] = f2bf(t[lx][rr]);
    }
}

// ------------------------------------------------------------------
// fp32 src[K][N] -> bf16 MFMA B-fragment tiles.
// Tile = 16 cols x 32 k.  Within tile: lane = (klocal>>3)*16 + collocal,
// j = k&7;  flat = (tile*64 + lane)*8 + j,  tile = tile_n*(K/32)+tile_k.
// Fragment load is then a per-lane contiguous 16B read.
// ------------------------------------------------------------------
__global__ __launch_bounds__(256) void repack_frag_kernel(const float* __restrict__ src,
                                                          unsigned short* __restrict__ dst,
                                                          int K, int N) {
    int idx = blockIdx.x * 256 + threadIdx.x;  // (tile, lane)
    int total = (N >> 4) * (K >> 5) * 64;
    if (idx >= total) return;
    int lane = idx & 63, tile = idx >> 6;
    int ktiles = K >> 5;
    int tile_n = tile / ktiles, tile_k = tile % ktiles;
    int col = tile_n * 16 + (lane & 15);
    int k0 = tile_k * 32 + (lane >> 4) * 8;
    __align__(16) unsigned short v[8];
#pragma unroll
    for (int j = 0; j < 8; j++) v[j] = f2bf(src[(size_t)(k0 + j) * N + col]);
    *(uint4*)(dst + (size_t)idx * 8) = *(const uint4*)v;
}

// ------------------------------------------------------------------
// fp32 x[b][t][c] -> xT[b][c][t]
// ------------------------------------------------------------------
__global__ __launch_bounds__(256) void transpose_x_kernel(const float* __restrict__ x,
                                                          float* __restrict__ xT) {
    __shared__ float tile[32][33];
    const int b = blockIdx.z;
    const int t0 = blockIdx.x * 32, c0 = blockIdx.y * 32;
    const int lx = threadIdx.x & 31, ly = threadIdx.x >> 5;
    const float* xp = x + (size_t)b * T_LEN * C_DIM;
    float* op = xT + (size_t)b * C_DIM * T_LEN;
    for (int rr = ly; rr < 32; rr += 8)
        tile[rr][lx] = xp[(size_t)(t0 + rr) * C_DIM + c0 + lx];
    __syncthreads();
    for (int rr = ly; rr < 32; rr += 8)
        op[(size_t)(c0 + rr) * T_LEN + t0 + lx] = tile[lx][rr];
}

// ------------------------------------------------------------------
// Per-(b,c) 4096-pt FFT, fused radix-2 stage-pairs, pad-32 LDS.
// ------------------------------------------------------------------
__global__ __launch_bounds__(256) void fft_mag_kernel(const float* __restrict__ src,
                                                      float* __restrict__ mags,
                                                      int transposed) {
    const int bx = blockIdx.x;
    const int b = bx >> 8;
    const int c = bx & 255;
    const int tid = threadIdx.x;

    __shared__ __align__(16) float re[4224];
    __shared__ __align__(16) float im[4224];
    __shared__ __align__(16) float twr[2048];
    __shared__ __align__(16) float twi[2048];

    for (int u = tid; u < 2048; u += 256) {
        float ang = -6.283185307179586f * (float)u / 4096.0f;
        float s, co;
        sincosf(ang, &s, &co);
        twr[u] = co;
        twi[u] = s;
    }
    for (int i = tid; i < 4224; i += 256) im[i] = 0.0f;

    if (transposed) {
        const float4* row = (const float4*)(src + ((size_t)(b * C_DIM + c)) * T_LEN);
        for (int e4 = tid; e4 < 1024; e4 += 256) {
            float4 v = row[e4];
            int e = e4 * 4;
            re[FPAD((int)(__brev((unsigned)(e + 0)) >> 20))] = v.x;
            re[FPAD((int)(__brev((unsigned)(e + 1)) >> 20))] = v.y;
            re[FPAD((int)(__brev((unsigned)(e + 2)) >> 20))] = v.z;
            re[FPAD((int)(__brev((unsigned)(e + 3)) >> 20))] = v.w;
        }
    } else {
        const float* xp = src + (size_t)b * T_LEN * C_DIM + c;
        for (int e = tid; e < 4096; e += 256) {
            int r = (int)(__brev((unsigned)e) >> 20);
            re[FPAD(r)] = xp[(size_t)e * C_DIM];
        }
    }
    __syncthreads();

#pragma unroll
    for (int sp = 0; sp < 6; sp++) {
        const int h = 1 << (2 * sp);
        const int t1s = 11 - 2 * sp;
        const int t2s = 10 - 2 * sp;
        for (int j = tid; j < 1024; j += 256) {
            int p = j & (h - 1);
            int G = j >> (2 * sp);
            int base = G * 4 * h + p;
            int iA = FPAD(base), iB = FPAD(base + h);
            int iC = FPAD(base + 2 * h), iD = FPAD(base + 3 * h);
            float w1r = twr[p << t1s], w1i = twi[p << t1s];
            float w2r = twr[p << t2s], w2i = twi[p << t2s];
            float Ar = re[iA], Ai = im[iA], Br = re[iB], Bi = im[iB];
            float Cr = re[iC], Ci = im[iC], Dr = re[iD], Di = im[iD];
            float tBr = w1r * Br - w1i * Bi, tBi = w1r * Bi + w1i * Br;
            float tDr = w1r * Dr - w1i * Di, tDi = w1r * Di + w1i * Dr;
            float A1r = Ar + tBr, A1i = Ai + tBi;
            float B1r = Ar - tBr, B1i = Ai - tBi;
            float C1r = Cr + tDr, C1i = Ci + tDi;
            float D1r = Cr - tDr, D1i = Ci - tDi;
            float tCr = w2r * C1r - w2i * C1i, tCi = w2r * C1i + w2i * C1r;
            float uDr = w2r * D1r - w2i * D1i, uDi = w2r * D1i + w2i * D1r;
            float vDr = uDi, vDi = -uDr;
            re[iA] = A1r + tCr; im[iA] = A1i + tCi;
            re[iC] = A1r - tCr; im[iC] = A1i - tCi;
            re[iB] = B1r + vDr; im[iB] = B1i + vDi;
            re[iD] = B1r - vDr; im[iD] = B1i - vDi;
        }
        __syncthreads();
    }

    float* mp = mags + ((size_t)(b * C_DIM + c)) * 2048;
    for (int u = tid; u < 2048; u += 256) {
        int f = FPAD(u + 1);
        mp[u] = sqrtf(re[f] * re[f] + im[f] * im[f]);
    }
}

// ------------------------------------------------------------------
// partial[b][cc][u] = sum over 32 channels of mags
// ------------------------------------------------------------------
__global__ __launch_bounds__(256) void reduce_amps_kernel(const float* __restrict__ mags,
                                                          float* __restrict__ partial) {
    const int b = blockIdx.z, cc = blockIdx.y;
    const int u = blockIdx.x * 256 + threadIdx.x;
    const float* mp = mags + ((size_t)b * C_DIM + cc * 32) * 2048 + u;
    float s = 0.0f;
    for (int c = 0; c < 32; c++) s += mp[(size_t)c * 2048];
    partial[((size_t)b * 8 + cc) * 2048 + u] = s;
}

// ------------------------------------------------------------------
// Per-batch top-4 (value desc, ties -> lower index), periods, softmax
// ------------------------------------------------------------------
__global__ __launch_bounds__(256) void topk_kernel(const float* __restrict__ partial,
                                                   int* __restrict__ meta_p,
                                                   float* __restrict__ meta_w) {
    const int b = blockIdx.x;
    const int tid = threadIdx.x;
    __shared__ float v[2048];
    __shared__ float rv[256];
    __shared__ int ri[256];
    __shared__ float topv[K_TOP];
    __shared__ int topi[K_TOP];

    for (int u = tid; u < 2048; u += 256) {
        float s = 0.0f;
        for (int cc = 0; cc < 8; cc++) s += partial[((size_t)b * 8 + cc) * 2048 + u];
        v[u] = s * (1.0f / (float)C_DIM);
    }

    for (int k = 0; k < K_TOP; k++) {
        __syncthreads();
        float bv = -1e30f;
        int bi = 2048;
        for (int u = tid; u < 2048; u += 256) {
            float val = v[u];
            if (val > bv) { bv = val; bi = u; }
        }
        rv[tid] = bv;
        ri[tid] = bi;
        __syncthreads();
        for (int s = 128; s > 0; s >>= 1) {
            if (tid < s) {
                float ov = rv[tid + s];
                int oi = ri[tid + s];
                if (ov > rv[tid] || (ov == rv[tid] && oi < ri[tid])) {
                    rv[tid] = ov;
                    ri[tid] = oi;
                }
            }
            __syncthreads();
        }
        if (tid == 0) {
            topv[k] = rv[0];
            topi[k] = ri[0];
            v[ri[0]] = -1e30f;
        }
    }
    __syncthreads();
    if (tid == 0) {
        float mx = topv[0];
        for (int k = 1; k < K_TOP; k++) mx = fmaxf(mx, topv[k]);
        float e[K_TOP], se = 0.0f;
        for (int k = 0; k < K_TOP; k++) { e[k] = expf(topv[k] - mx); se += e[k]; }
        for (int k = 0; k < K_TOP; k++) {
            int idx = topi[k];
            int d = (idx >= 1) ? idx : 1;
            int p = T_LEN / d;
            if (p < 1) p = 1;
            meta_p[b * K_TOP + k] = p;
            meta_w[b * K_TOP + k] = e[k] / se;
        }
    }
}

// ------------------------------------------------------------------
// Conv as MFMA GEMM, batched over k via blockIdx.z.
// dst = convbufs + z*conv_stride; k = koff + z.
// ------------------------------------------------------------------
__global__ __launch_bounds__(256) void conv_mfma_kernel(const unsigned short* __restrict__ xbf,
                                                        const unsigned short* __restrict__ WcT,
                                                        const float* __restrict__ bc,
                                                        const int* __restrict__ meta_p,
                                                        const unsigned short* __restrict__ zbuf,
                                                        unsigned short* __restrict__ convbufs,
                                                        size_t conv_stride, int koff) {
    const int b = blockIdx.y;
    const int kz = blockIdx.z;
    const int n = meta_p[b * K_TOP + koff + kz];
    const int tile_n = blockIdx.x & 1;
    const int tile_m = blockIdx.x >> 1;
    const int row0 = tile_m * 128, c0 = tile_n * 128;
    const int tid = threadIdx.x, w = tid >> 6, lane = tid & 63;
    const int wm = w >> 1, wn = w & 1;

    __shared__ __align__(16) unsigned short Al[128 * 32];
    __shared__ __align__(16) unsigned short Bl[128 * 32];

    int ti[2], tj[2];
#pragma unroll
    for (int s = 0; s < 2; s++) {
        int t = row0 + s * 64 + (tid >> 2);
        int ii = t / n;
        ti[s] = ii;
        tj[s] = t - ii * n;
    }
    const unsigned short* xb = xbf + (size_t)b * T_LEN * C_DIM;
    const int lco = (tid & 3) * 8;

    f32x4 acc[4][4];
#pragma unroll
    for (int m = 0; m < 4; m++)
#pragma unroll
        for (int nn = 0; nn < 4; nn++) acc[m][nn] = (f32x4){0.f, 0.f, 0.f, 0.f};

    for (int q = 0; q < 9; q++) {
        const int di = q / 3 - 1, dj = q % 3 - 1;
        const unsigned short* baseA[2];
        const unsigned short* baseB[2];
#pragma unroll
        for (int s = 0; s < 2; s++) {
            int ii = ti[s] + di, jj = tj[s] + dj;
            int tp = ii * n + jj;
            bool ok = (jj >= 0) && (jj < n) && (ii >= 0) && (tp < T_LEN);
            baseA[s] = ok ? (xb + (size_t)tp * C_DIM + lco) : (zbuf + lco);
            baseB[s] = WcT + (size_t)(c0 + s * 64 + (tid >> 2)) * 2304 + q * 256 + lco;
        }
        for (int kc = 0; kc < 8; kc++) {
            __syncthreads();
#pragma unroll
            for (int s = 0; s < 2; s++) {
                lds_load16(baseA[s] + kc * 32, &Al[(s * 4 + w) * 512]);
                lds_load16(baseB[s] + kc * 32, &Bl[(s * 4 + w) * 512]);
            }
            __syncthreads();

            bf16x8 af[4], bfr[4];
#pragma unroll
            for (int m = 0; m < 4; m++)
                af[m] = *(const bf16x8*)&Al[(wm * 64 + m * 16 + (lane & 15)) * 32 + (lane >> 4) * 8];
#pragma unroll
            for (int nn = 0; nn < 4; nn++)
                bfr[nn] = *(const bf16x8*)&Bl[(wn * 64 + nn * 16 + (lane & 15)) * 32 + (lane >> 4) * 8];
#pragma unroll
            for (int m = 0; m < 4; m++)
#pragma unroll
                for (int nn = 0; nn < 4; nn++)
                    acc[m][nn] = __builtin_amdgcn_mfma_f32_16x16x32_bf16(af[m], bfr[nn], acc[m][nn], 0, 0, 0);
        }
    }

    unsigned short* ob = convbufs + (size_t)kz * conv_stride + (size_t)b * T_LEN * C_DIM;
#pragma unroll
    for (int nn = 0; nn < 4; nn++) {
        int col = c0 + wn * 64 + nn * 16 + (lane & 15);
        float bs = bc[col];
#pragma unroll
        for (int m = 0; m < 4; m++) {
            int rbase = row0 + wm * 64 + m * 16 + (lane >> 4) * 4;
#pragma unroll
            for (int r = 0; r < 4; r++) {
                float v = acc[m][nn][r] + bs;
                ob[(size_t)(rbase + r) * C_DIM + col] = f2bf(gelu_exact(v));
            }
        }
    }
}

// ------------------------------------------------------------------
// Fused FeedForward over k:  out[strip] += sum_k (wk*gelu(A_k@W1+b1))@W2 + b2
// Block: 512 thr (8 waves), 128-row strip, full N=256.
// A_k: 64KB swizzled LDS (reg-staged).  hidden: 128x128 chunks, gelu'd,
// wk-scaled, bf16 -> swizzled LDS, immediately consumed by GEMM2.
// W1frag/W2frag: B-fragment-tiled global (direct per-lane 16B loads).
// XOR swizzle: byte ^= (row&7)<<4  -> 2-way LDS conflicts max.
// ------------------------------------------------------------------
__global__ __launch_bounds__(512, 2) void fused_ff_kernel(
    const unsigned short* __restrict__ convbufs, size_t conv_stride,
    const unsigned short* __restrict__ W1frag,
    const unsigned short* __restrict__ W2frag,
    const float* __restrict__ b1,
    const float* __restrict__ b2,
    const float* __restrict__ meta_w,
    float* __restrict__ out,
    int koff, int kcount) {
    const int tid = threadIdx.x;
    const int w = tid >> 6, lane = tid & 63;
    const int wm = w >> 2, wn = w & 3;
    const int row0 = blockIdx.x * 128;
    const int b = row0 >> 12;

    __shared__ __align__(16) unsigned short Asw[128 * 256];  // 64 KB
    __shared__ __align__(16) unsigned short Hsw[128 * 128];  // 32 KB
    __shared__ float b1s[1024];

    for (int i = tid; i < 1024; i += 512) b1s[i] = b1[i];

    f32x4 acc2[4][4];
#pragma unroll
    for (int m = 0; m < 4; m++)
#pragma unroll
        for (int nn = 0; nn < 4; nn++) acc2[m][nn] = (f32x4){0.f, 0.f, 0.f, 0.f};

    for (int kk = koff; kk < koff + kcount; kk++) {
        const float wk = meta_w[b * K_TOP + kk];
        const unsigned short* Ag =
            convbufs + (size_t)(kk - koff) * conv_stride + (size_t)row0 * C_DIM;

        // ---- stage A strip into swizzled LDS (8 x 16B per thread) ----
        uint4 tmp[8];
#pragma unroll
        for (int u = 0; u < 8; u++) {
            int ch = u * 512 + tid;  // 16B chunk id
            tmp[u] = *(const uint4*)(Ag + (size_t)ch * 8);
        }
        // last barrier executed guarantees no wave still reads Asw
#pragma unroll
        for (int u = 0; u < 8; u++) {
            int ch = u * 512 + tid;
            int row = ch >> 5, cb = (ch & 31) * 16;
            *(uint4*)((char*)Asw + row * 512 + (cb ^ ((row & 7) << 4))) = tmp[u];
        }
        __syncthreads();

        for (int cc = 0; cc < 8; cc++) {
            // ---- GEMM1: h[128x128] chunk ----
            f32x4 acc1[4][2];
#pragma unroll
            for (int m = 0; m < 4; m++)
#pragma unroll
                for (int n2 = 0; n2 < 2; n2++) acc1[m][n2] = (f32x4){0.f, 0.f, 0.f, 0.f};

#pragma unroll
            for (int ks = 0; ks < 8; ks++) {
                bf16x8 af[4], bf1[2];
#pragma unroll
                for (int m = 0; m < 4; m++) {
                    int row = wm * 64 + m * 16 + (lane & 15);
                    int cb = ks * 64 + (lane >> 4) * 16;
                    af[m] = *(const bf16x8*)((char*)Asw + row * 512 + (cb ^ ((row & 7) << 4)));
                }
#pragma unroll
                for (int n2 = 0; n2 < 2; n2++) {
                    int tile_n = cc * 8 + wn * 2 + n2;
                    bf1[n2] = *(const bf16x8*)(W1frag + ((size_t)(tile_n * 8 + ks) * 64 + lane) * 8);
                }
#pragma unroll
                for (int m = 0; m < 4; m++)
#pragma unroll
                    for (int n2 = 0; n2 < 2; n2++)
                        acc1[m][n2] = __builtin_amdgcn_mfma_f32_16x16x32_bf16(af[m], bf1[n2],
                                                                              acc1[m][n2], 0, 0, 0);
            }

            // ---- gelu + wk-scale -> Hsw (bf16, swizzled) ----
#pragma unroll
            for (int m = 0; m < 4; m++)
#pragma unroll
                for (int n2 = 0; n2 < 2; n2++) {
                    int coll = wn * 32 + n2 * 16 + (lane & 15);
                    float bb = b1s[cc * 128 + coll];
#pragma unroll
                    for (int r = 0; r < 4; r++) {
                        int row = wm * 64 + m * 16 + (lane >> 4) * 4 + r;
                        unsigned short hv = f2bf(wk * gelu_exact(acc1[m][n2][r] + bb));
                        *(unsigned short*)((char*)Hsw + row * 256 +
                                           ((coll * 2) ^ ((row & 7) << 4))) = hv;
                    }
                }
            __syncthreads();

            // ---- GEMM2: acc2 += h_chunk @ W2chunk ----
#pragma unroll
            for (int ks2 = 0; ks2 < 4; ks2++) {
                bf16x8 af2[4], bf2[4];
#pragma unroll
                for (int m = 0; m < 4; m++) {
                    int row = wm * 64 + m * 16 + (lane & 15);
                    int cb = ks2 * 64 + (lane >> 4) * 16;
                    af2[m] = *(const bf16x8*)((char*)Hsw + row * 256 + (cb ^ ((row & 7) << 4)));
                }
#pragma unroll
                for (int nn = 0; nn < 4; nn++) {
                    int tile_n = wn * 4 + nn;
                    int tile_k = cc * 4 + ks2;
                    bf2[nn] = *(const bf16x8*)(W2frag + ((size_t)(tile_n * 32 + tile_k) * 64 + lane) * 8);
                }
#pragma unroll
                for (int m = 0; m < 4; m++)
#pragma unroll
                    for (int nn = 0; nn < 4; nn++)
                        acc2[m][nn] = __builtin_amdgcn_mfma_f32_16x16x32_bf16(af2[m], bf2[nn],
                                                                              acc2[m][nn], 0, 0, 0);
            }
            __syncthreads();
        }
    }

    // ---- epilogue: out += acc2 + b2  (sum_k wk == 1) ----
#pragma unroll
    for (int nn = 0; nn < 4; nn++) {
        int col = wn * 64 + nn * 16 + (lane & 15);
        float bb = b2[col];
#pragma unroll
        for (int m = 0; m < 4; m++) {
            int rbase = row0 + wm * 64 + m * 16 + (lane >> 4) * 4;
#pragma unroll
            for (int r = 0; r < 4; r++)
                out[(size_t)(rbase + r) * C_DIM + col] += acc2[m][nn][r] + bb;
        }
    }
}

// ------------------------------------------------------------------
extern "C" void kernel_launch(void* const* d_in, const int* in_sizes, int n_in,
                              void* d_out, int out_size, void* d_ws, size_t ws_size,
                              hipStream_t stream) {
    const float* x  = (const float*)d_in[0];
    const float* Wc = (const float*)d_in[1];
    const float* bc = (const float*)d_in[2];
    const float* W1 = (const float*)d_in[3];
    const float* b1 = (const float*)d_in[4];
    const float* W2 = (const float*)d_in[5];
    const float* b2 = (const float*)d_in[6];
    float* out = (float*)d_out;

    const size_t CONV_ELEMS = (size_t)B_DIM * T_LEN * C_DIM;  // 8M
    const size_t CONV_BYTES = CONV_ELEMS * 2;                 // 16.78 MB
    const size_t MAGS_BYTES = (size_t)B_DIM * C_DIM * 2048 * 4;  // 16.78 MB
    const size_t XT_BYTES = (size_t)B_DIM * T_LEN * C_DIM * 4;   // 33.55 MB

    // ---- fixed carve ----
    uint8_t* ws = (uint8_t*)d_ws;
    size_t off = 0;
    auto alloc = [&](size_t bytes) {
        size_t o = off;
        off = (off + bytes + 255) & ~(size_t)255;
        return o;
    };
    float* partial = (float*)(ws + alloc((size_t)B_DIM * 8 * 2048 * 4));
    int* meta_p = (int*)(ws + alloc(B_DIM * K_TOP * 4));
    float* meta_w = (float*)(ws + alloc(B_DIM * K_TOP * 4));
    unsigned short* xbf = (unsigned short*)(ws + alloc((size_t)B_DIM * T_LEN * C_DIM * 2));
    unsigned short* WcT = (unsigned short*)(ws + alloc((size_t)256 * 2304 * 2));
    unsigned short* W1frag = (unsigned short*)(ws + alloc((size_t)256 * 1024 * 2));
    unsigned short* W2frag = (unsigned short*)(ws + alloc((size_t)1024 * 256 * 2));
    unsigned short* zbuf = (unsigned short*)(ws + alloc(512));

    // ---- tiered regionA ----
    size_t remaining = (ws_size > off) ? (ws_size - off) : 0;
    uint8_t* regionA = ws + off;
    int tier;  // 2=FULL(4 convbufs), 1=MID(1 convbuf + xT), 0=MIN(1 convbuf, no xT)
    if (remaining >= 4 * CONV_BYTES) tier = 2;
    else if (remaining >= MAGS_BYTES + XT_BYTES) tier = 1;
    else tier = 0;

    float* mags = (float*)regionA;  // FFT phase (dead before conv)
    float* xT = (float*)(regionA + ((tier == 2) ? CONV_BYTES : MAGS_BYTES));
    unsigned short* convbufs = (unsigned short*)regionA;
    const int use_xT = (tier >= 1);

    // 1. out = x ; xbf = bf16(x) ; zero page
    cvt_x_kernel<<<dim3((B_DIM * T_LEN * C_DIM / 4) / 256), 256, 0, stream>>>(
        (const float4*)x, (float4*)out, (ushort4*)xbf, zbuf);

    // 2. weight prep: WcT transpose; W1/W2 -> fragment tiles
    transpose_cvt_kernel<<<dim3(256 / 32, 2304 / 32), 256, 0, stream>>>(Wc, WcT, 2304, 256);
    repack_frag_kernel<<<dim3(128), 256, 0, stream>>>(W1, W1frag, 256, 1024);
    repack_frag_kernel<<<dim3(128), 256, 0, stream>>>(W2, W2frag, 1024, 256);

    // 3. FFT magnitudes, reduce, top-4
    if (use_xT) {
        transpose_x_kernel<<<dim3(T_LEN / 32, C_DIM / 32, B_DIM), 256, 0, stream>>>(x, xT);
        fft_mag_kernel<<<dim3(B_DIM * C_DIM), 256, 0, stream>>>(xT, mags, 1);
    } else {
        fft_mag_kernel<<<dim3(B_DIM * C_DIM), 256, 0, stream>>>(x, mags, 0);
    }
    reduce_amps_kernel<<<dim3(2048 / 256, 8, B_DIM), 256, 0, stream>>>(mags, partial);
    topk_kernel<<<dim3(B_DIM), 256, 0, stream>>>(partial, meta_p, meta_w);

    // 4. conv (all k) then fused FF (all k)
    if (tier == 2) {
        conv_mfma_kernel<<<dim3(64, B_DIM, K_TOP), 256, 0, stream>>>(
            xbf, WcT, bc, meta_p, zbuf, convbufs, CONV_ELEMS, 0);
        fused_ff_kernel<<<dim3(B_DIM * T_LEN / 128), 512, 0, stream>>>(
            convbufs, CONV_ELEMS, W1frag, W2frag, b1, b2, meta_w, out, 0, K_TOP);
    } else {
        for (int k = 0; k < K_TOP; k++) {
            conv_mfma_kernel<<<dim3(64, B_DIM, 1), 256, 0, stream>>>(
                xbf, WcT, bc, meta_p, zbuf, convbufs, 0, k);
            fused_ff_kernel<<<dim3(B_DIM * T_LEN / 128), 512, 0, stream>>>(
                convbufs, 0, W1frag, W2frag, b1, b2, meta_w, out, k, 1);
        }
    }
}

// Round 7
// 479.406 us; speedup vs baseline: 11.4049x; 1.0996x over previous
//
#include <hip/hip_runtime.h>
#include <cstdint>
#include <cstddef>

#define T_LEN 4096
#define C_DIM 256
#define B_DIM 8
#define K_TOP 4

typedef __attribute__((ext_vector_type(8))) short bf16x8;
typedef __attribute__((ext_vector_type(4))) float f32x4;

__device__ __forceinline__ float gelu_exact(float x) {
    return 0.5f * x * (1.0f + erff(x * 0.70710678118654752f));
}

__device__ __forceinline__ unsigned short f2bf(float f) {
    uint32_t u = __float_as_uint(f);
    uint32_t r = (u + 0x7fffu + ((u >> 16) & 1u)) >> 16;
    return (unsigned short)r;
}

typedef __attribute__((address_space(3))) uint32_t lds_u32_t;
typedef __attribute__((address_space(1))) const uint32_t gbl_u32_t;

__device__ __forceinline__ void lds_load16(const void* g, void* l) {
    __builtin_amdgcn_global_load_lds((gbl_u32_t*)g, (lds_u32_t*)l, 16, 0, 0);
}

// padded LDS index for FFT: +1 float per 32
#define FPAD(i) ((i) + ((i) >> 5))

// ------------------------------------------------------------------
// out = x  AND  xbf = bf16(x)  (single read of x), plus zero page
// ------------------------------------------------------------------
__global__ __launch_bounds__(256) void cvt_x_kernel(const float4* __restrict__ x,
                                                    float4* __restrict__ out,
                                                    ushort4* __restrict__ xbf,
                                                    unsigned short* __restrict__ zbuf) {
    size_t i = (size_t)blockIdx.x * 256 + threadIdx.x;
    float4 v = x[i];
    out[i] = v;
    ushort4 o;
    o.x = f2bf(v.x); o.y = f2bf(v.y); o.z = f2bf(v.z); o.w = f2bf(v.w);
    xbf[i] = o;
    if (blockIdx.x == 0 && threadIdx.x < 256) zbuf[threadIdx.x] = 0;
}

// ------------------------------------------------------------------
// fp32 [R][C] -> bf16 transposed [C][R]   (conv weights)
// ------------------------------------------------------------------
__global__ __launch_bounds__(256) void transpose_cvt_kernel(const float* __restrict__ src,
                                                            unsigned short* __restrict__ dst,
                                                            int R, int C) {
    __shared__ float t[32][33];
    const int c0 = blockIdx.x * 32, r0 = blockIdx.y * 32;
    const int lx = threadIdx.x & 31, ly = threadIdx.x >> 5;
    for (int rr = ly; rr < 32; rr += 8) {
        int r = r0 + rr, c = c0 + lx;
        t[rr][lx] = (r < R && c < C) ? src[(size_t)r * C + c] : 0.0f;
    }
    __syncthreads();
    for (int rr = ly; rr < 32; rr += 8) {
        int c = c0 + rr, r = r0 + lx;
        if (r < R && c < C) dst[(size_t)c * R + r] = f2bf(t[lx][rr]);
    }
}

// ------------------------------------------------------------------
// fp32 src[K][N] -> bf16 MFMA B-fragment tiles (for fused FF).
// ------------------------------------------------------------------
__global__ __launch_bounds__(256) void repack_frag_kernel(const float* __restrict__ src,
                                                          unsigned short* __restrict__ dst,
                                                          int K, int N) {
    int idx = blockIdx.x * 256 + threadIdx.x;  // (tile, lane)
    int total = (N >> 4) * (K >> 5) * 64;
    if (idx >= total) return;
    int lane = idx & 63, tile = idx >> 6;
    int ktiles = K >> 5;
    int tile_n = tile / ktiles, tile_k = tile % ktiles;
    int col = tile_n * 16 + (lane & 15);
    int k0 = tile_k * 32 + (lane >> 4) * 8;
    __align__(16) unsigned short v[8];
#pragma unroll
    for (int j = 0; j < 8; j++) v[j] = f2bf(src[(size_t)(k0 + j) * N + col]);
    *(uint4*)(dst + (size_t)idx * 8) = *(const uint4*)v;
}

// ------------------------------------------------------------------
// fp32 x[b][t][c] -> xT[b][c][t]
// ------------------------------------------------------------------
__global__ __launch_bounds__(256) void transpose_x_kernel(const float* __restrict__ x,
                                                          float* __restrict__ xT) {
    __shared__ float tile[32][33];
    const int b = blockIdx.z;
    const int t0 = blockIdx.x * 32, c0 = blockIdx.y * 32;
    const int lx = threadIdx.x & 31, ly = threadIdx.x >> 5;
    const float* xp = x + (size_t)b * T_LEN * C_DIM;
    float* op = xT + (size_t)b * C_DIM * T_LEN;
    for (int rr = ly; rr < 32; rr += 8)
        tile[rr][lx] = xp[(size_t)(t0 + rr) * C_DIM + c0 + lx];
    __syncthreads();
    for (int rr = ly; rr < 32; rr += 8)
        op[(size_t)(c0 + rr) * T_LEN + t0 + lx] = tile[lx][rr];
}

// ------------------------------------------------------------------
// Per-(b,c) 4096-pt FFT, fused radix-2 stage-pairs, pad-32 LDS.
// ------------------------------------------------------------------
__global__ __launch_bounds__(256) void fft_mag_kernel(const float* __restrict__ src,
                                                      float* __restrict__ mags,
                                                      int transposed) {
    const int bx = blockIdx.x;
    const int b = bx >> 8;
    const int c = bx & 255;
    const int tid = threadIdx.x;

    __shared__ __align__(16) float re[4224];
    __shared__ __align__(16) float im[4224];
    __shared__ __align__(16) float twr[2048];
    __shared__ __align__(16) float twi[2048];

    for (int u = tid; u < 2048; u += 256) {
        float ang = -6.283185307179586f * (float)u / 4096.0f;
        float s, co;
        sincosf(ang, &s, &co);
        twr[u] = co;
        twi[u] = s;
    }
    for (int i = tid; i < 4224; i += 256) im[i] = 0.0f;

    if (transposed) {
        const float4* row = (const float4*)(src + ((size_t)(b * C_DIM + c)) * T_LEN);
        for (int e4 = tid; e4 < 1024; e4 += 256) {
            float4 v = row[e4];
            int e = e4 * 4;
            re[FPAD((int)(__brev((unsigned)(e + 0)) >> 20))] = v.x;
            re[FPAD((int)(__brev((unsigned)(e + 1)) >> 20))] = v.y;
            re[FPAD((int)(__brev((unsigned)(e + 2)) >> 20))] = v.z;
            re[FPAD((int)(__brev((unsigned)(e + 3)) >> 20))] = v.w;
        }
    } else {
        const float* xp = src + (size_t)b * T_LEN * C_DIM + c;
        for (int e = tid; e < 4096; e += 256) {
            int r = (int)(__brev((unsigned)e) >> 20);
            re[FPAD(r)] = xp[(size_t)e * C_DIM];
        }
    }
    __syncthreads();

#pragma unroll
    for (int sp = 0; sp < 6; sp++) {
        const int h = 1 << (2 * sp);
        const int t1s = 11 - 2 * sp;
        const int t2s = 10 - 2 * sp;
        for (int j = tid; j < 1024; j += 256) {
            int p = j & (h - 1);
            int G = j >> (2 * sp);
            int base = G * 4 * h + p;
            int iA = FPAD(base), iB = FPAD(base + h);
            int iC = FPAD(base + 2 * h), iD = FPAD(base + 3 * h);
            float w1r = twr[p << t1s], w1i = twi[p << t1s];
            float w2r = twr[p << t2s], w2i = twi[p << t2s];
            float Ar = re[iA], Ai = im[iA], Br = re[iB], Bi = im[iB];
            float Cr = re[iC], Ci = im[iC], Dr = re[iD], Di = im[iD];
            float tBr = w1r * Br - w1i * Bi, tBi = w1r * Bi + w1i * Br;
            float tDr = w1r * Dr - w1i * Di, tDi = w1r * Di + w1i * Dr;
            float A1r = Ar + tBr, A1i = Ai + tBi;
            float B1r = Ar - tBr, B1i = Ai - tBi;
            float C1r = Cr + tDr, C1i = Ci + tDi;
            float D1r = Cr - tDr, D1i = Ci - tDi;
            float tCr = w2r * C1r - w2i * C1i, tCi = w2r * C1i + w2i * C1r;
            float uDr = w2r * D1r - w2i * D1i, uDi = w2r * D1i + w2i * D1r;
            float vDr = uDi, vDi = -uDr;
            re[iA] = A1r + tCr; im[iA] = A1i + tCi;
            re[iC] = A1r - tCr; im[iC] = A1i - tCi;
            re[iB] = B1r + vDr; im[iB] = B1i + vDi;
            re[iD] = B1r - vDr; im[iD] = B1i - vDi;
        }
        __syncthreads();
    }

    float* mp = mags + ((size_t)(b * C_DIM + c)) * 2048;
    for (int u = tid; u < 2048; u += 256) {
        int f = FPAD(u + 1);
        mp[u] = sqrtf(re[f] * re[f] + im[f] * im[f]);
    }
}

// ------------------------------------------------------------------
// partial[b][cc][u] = sum over 32 channels of mags
// ------------------------------------------------------------------
__global__ __launch_bounds__(256) void reduce_amps_kernel(const float* __restrict__ mags,
                                                          float* __restrict__ partial) {
    const int b = blockIdx.z, cc = blockIdx.y;
    const int u = blockIdx.x * 256 + threadIdx.x;
    const float* mp = mags + ((size_t)b * C_DIM + cc * 32) * 2048 + u;
    float s = 0.0f;
    for (int c = 0; c < 32; c++) s += mp[(size_t)c * 2048];
    partial[((size_t)b * 8 + cc) * 2048 + u] = s;
}

// ------------------------------------------------------------------
// Per-batch top-4 (value desc, ties -> lower index), periods, softmax
// ------------------------------------------------------------------
__global__ __launch_bounds__(256) void topk_kernel(const float* __restrict__ partial,
                                                   int* __restrict__ meta_p,
                                                   float* __restrict__ meta_w) {
    const int b = blockIdx.x;
    const int tid = threadIdx.x;
    __shared__ float v[2048];
    __shared__ float rv[256];
    __shared__ int ri[256];
    __shared__ float topv[K_TOP];
    __shared__ int topi[K_TOP];

    for (int u = tid; u < 2048; u += 256) {
        float s = 0.0f;
        for (int cc = 0; cc < 8; cc++) s += partial[((size_t)b * 8 + cc) * 2048 + u];
        v[u] = s * (1.0f / (float)C_DIM);
    }

    for (int k = 0; k < K_TOP; k++) {
        __syncthreads();
        float bv = -1e30f;
        int bi = 2048;
        for (int u = tid; u < 2048; u += 256) {
            float val = v[u];
            if (val > bv) { bv = val; bi = u; }
        }
        rv[tid] = bv;
        ri[tid] = bi;
        __syncthreads();
        for (int s = 128; s > 0; s >>= 1) {
            if (tid < s) {
                float ov = rv[tid + s];
                int oi = ri[tid + s];
                if (ov > rv[tid] || (ov == rv[tid] && oi < ri[tid])) {
                    rv[tid] = ov;
                    ri[tid] = oi;
                }
            }
            __syncthreads();
        }
        if (tid == 0) {
            topv[k] = rv[0];
            topi[k] = ri[0];
            v[ri[0]] = -1e30f;
        }
    }
    __syncthreads();
    if (tid == 0) {
        float mx = topv[0];
        for (int k = 1; k < K_TOP; k++) mx = fmaxf(mx, topv[k]);
        float e[K_TOP], se = 0.0f;
        for (int k = 0; k < K_TOP; k++) { e[k] = expf(topv[k] - mx); se += e[k]; }
        for (int k = 0; k < K_TOP; k++) {
            int idx = topi[k];
            int d = (idx >= 1) ? idx : 1;
            int p = T_LEN / d;
            if (p < 1) p = 1;
            meta_p[b * K_TOP + k] = p;
            meta_w[b * K_TOP + k] = e[k] / se;
        }
    }
}

// ------------------------------------------------------------------
// Conv as MFMA GEMM v2: 128x256 tile (N whole), 512 thr / 8 waves,
// double-buffered min-2-phase K-loop (1 barrier per K-step, stage
// issued BEFORE MFMA so load latency hides under compute), and
// T2-lite XOR swizzle via per-lane global source permute (LDS dest
// stays linear; read side applies the same XOR) -> 2-way conflicts.
// Per wave: 64x64 output (acc[4][4]).  K = 9q * 256c, BK=32.
// ------------------------------------------------------------------
__global__ __launch_bounds__(512) void conv_mfma_kernel(const unsigned short* __restrict__ xbf,
                                                        const unsigned short* __restrict__ WcT,
                                                        const float* __restrict__ bc,
                                                        const int* __restrict__ meta_p,
                                                        const unsigned short* __restrict__ zbuf,
                                                        unsigned short* __restrict__ convbufs,
                                                        size_t conv_stride, int koff) {
    const int b = blockIdx.y;
    const int kz = blockIdx.z;
    const int n = meta_p[b * K_TOP + koff + kz];
    const int row0 = blockIdx.x * 128;
    const int tid = threadIdx.x, w = tid >> 6, lane = tid & 63;
    const int wm = w >> 2, wn = w & 3;

    __shared__ __align__(16) unsigned short Al[2][128 * 32];  // 8 KB each
    __shared__ __align__(16) unsigned short Bl[2][256 * 32];  // 16 KB each

    // staged row (1 A-row + 2 B-rows per thread), swizzled source chunk
    const int ra = tid >> 2;
    const int swz = ((tid & 3) ^ (ra & 3)) * 8;  // element offset
    int ti, tj;
    {
        int t = row0 + ra;
        ti = t / n;
        tj = t - ti * n;
    }
    const unsigned short* xb = xbf + (size_t)b * T_LEN * C_DIM;
    const unsigned short* baseB0 = WcT + (size_t)ra * 2304 + swz;
    const unsigned short* baseB1 = WcT + (size_t)(ra + 128) * 2304 + swz;

    auto computeA = [&](int q) -> const unsigned short* {
        int di = q / 3 - 1, dj = q % 3 - 1;
        int ii = ti + di, jj = tj + dj;
        int tp = ii * n + jj;
        bool ok = (jj >= 0) && (jj < n) && (ii >= 0) && (tp < T_LEN);
        return ok ? (xb + (size_t)tp * C_DIM + swz) : (zbuf + swz);
    };

    f32x4 acc[4][4];
#pragma unroll
    for (int m = 0; m < 4; m++)
#pragma unroll
        for (int nn = 0; nn < 4; nn++) acc[m][nn] = (f32x4){0.f, 0.f, 0.f, 0.f};

    // prologue: stage ks=0 into buf 0
    const unsigned short* baseA = computeA(0);
    lds_load16(baseA, &Al[0][tid * 8]);
    lds_load16(baseB0, &Bl[0][tid * 8]);
    lds_load16(baseB1, &Bl[0][4096 + tid * 8]);
    __syncthreads();

#pragma unroll 2
    for (int ks = 0; ks < 72; ks++) {
        const int cur = ks & 1;
        if (ks < 71) {
            int s = ks + 1;
            if ((s & 7) == 0) baseA = computeA(s >> 3);
            lds_load16(baseA + (s & 7) * 32, &Al[cur ^ 1][tid * 8]);
            lds_load16(baseB0 + s * 32, &Bl[cur ^ 1][tid * 8]);
            lds_load16(baseB1 + s * 32, &Bl[cur ^ 1][4096 + tid * 8]);
        }

        bf16x8 af[4], bfr[4];
#pragma unroll
        for (int m = 0; m < 4; m++) {
            int row = wm * 64 + m * 16 + (lane & 15);
            af[m] = *(const bf16x8*)((const char*)&Al[cur][0] + row * 64 +
                                     (((lane >> 4) * 16) ^ ((row & 3) << 4)));
        }
#pragma unroll
        for (int nn = 0; nn < 4; nn++) {
            int rowb = wn * 64 + nn * 16 + (lane & 15);
            bfr[nn] = *(const bf16x8*)((const char*)&Bl[cur][0] + rowb * 64 +
                                       (((lane >> 4) * 16) ^ ((rowb & 3) << 4)));
        }
#pragma unroll
        for (int m = 0; m < 4; m++)
#pragma unroll
            for (int nn = 0; nn < 4; nn++)
                acc[m][nn] = __builtin_amdgcn_mfma_f32_16x16x32_bf16(af[m], bfr[nn], acc[m][nn], 0, 0, 0);

        __syncthreads();  // drains this step's prefetch (vmcnt0) + read fence
    }

    unsigned short* ob = convbufs + (size_t)kz * conv_stride + (size_t)b * T_LEN * C_DIM;
#pragma unroll
    for (int nn = 0; nn < 4; nn++) {
        int col = wn * 64 + nn * 16 + (lane & 15);
        float bs = bc[col];
#pragma unroll
        for (int m = 0; m < 4; m++) {
            int rbase = row0 + wm * 64 + m * 16 + (lane >> 4) * 4;
#pragma unroll
            for (int r = 0; r < 4; r++) {
                float v = acc[m][nn][r] + bs;
                ob[(size_t)(rbase + r) * C_DIM + col] = f2bf(gelu_exact(v));
            }
        }
    }
}

// ------------------------------------------------------------------
// Fused FeedForward over k:  out[strip] += sum_k (wk*gelu(A_k@W1+b1))@W2 + b2
// ------------------------------------------------------------------
__global__ __launch_bounds__(512, 2) void fused_ff_kernel(
    const unsigned short* __restrict__ convbufs, size_t conv_stride,
    const unsigned short* __restrict__ W1frag,
    const unsigned short* __restrict__ W2frag,
    const float* __restrict__ b1,
    const float* __restrict__ b2,
    const float* __restrict__ meta_w,
    float* __restrict__ out,
    int koff, int kcount) {
    const int tid = threadIdx.x;
    const int w = tid >> 6, lane = tid & 63;
    const int wm = w >> 2, wn = w & 3;
    const int row0 = blockIdx.x * 128;
    const int b = row0 >> 12;

    __shared__ __align__(16) unsigned short Asw[128 * 256];  // 64 KB
    __shared__ __align__(16) unsigned short Hsw[128 * 128];  // 32 KB
    __shared__ float b1s[1024];

    for (int i = tid; i < 1024; i += 512) b1s[i] = b1[i];

    f32x4 acc2[4][4];
#pragma unroll
    for (int m = 0; m < 4; m++)
#pragma unroll
        for (int nn = 0; nn < 4; nn++) acc2[m][nn] = (f32x4){0.f, 0.f, 0.f, 0.f};

    for (int kk = koff; kk < koff + kcount; kk++) {
        const float wk = meta_w[b * K_TOP + kk];
        const unsigned short* Ag =
            convbufs + (size_t)(kk - koff) * conv_stride + (size_t)row0 * C_DIM;

        uint4 tmp[8];
#pragma unroll
        for (int u = 0; u < 8; u++) {
            int ch = u * 512 + tid;
            tmp[u] = *(const uint4*)(Ag + (size_t)ch * 8);
        }
#pragma unroll
        for (int u = 0; u < 8; u++) {
            int ch = u * 512 + tid;
            int row = ch >> 5, cb = (ch & 31) * 16;
            *(uint4*)((char*)Asw + row * 512 + (cb ^ ((row & 7) << 4))) = tmp[u];
        }
        __syncthreads();

        for (int cc = 0; cc < 8; cc++) {
            f32x4 acc1[4][2];
#pragma unroll
            for (int m = 0; m < 4; m++)
#pragma unroll
                for (int n2 = 0; n2 < 2; n2++) acc1[m][n2] = (f32x4){0.f, 0.f, 0.f, 0.f};

#pragma unroll
            for (int ks = 0; ks < 8; ks++) {
                bf16x8 af[4], bf1[2];
#pragma unroll
                for (int m = 0; m < 4; m++) {
                    int row = wm * 64 + m * 16 + (lane & 15);
                    int cb = ks * 64 + (lane >> 4) * 16;
                    af[m] = *(const bf16x8*)((char*)Asw + row * 512 + (cb ^ ((row & 7) << 4)));
                }
#pragma unroll
                for (int n2 = 0; n2 < 2; n2++) {
                    int tile_n = cc * 8 + wn * 2 + n2;
                    bf1[n2] = *(const bf16x8*)(W1frag + ((size_t)(tile_n * 8 + ks) * 64 + lane) * 8);
                }
#pragma unroll
                for (int m = 0; m < 4; m++)
#pragma unroll
                    for (int n2 = 0; n2 < 2; n2++)
                        acc1[m][n2] = __builtin_amdgcn_mfma_f32_16x16x32_bf16(af[m], bf1[n2],
                                                                              acc1[m][n2], 0, 0, 0);
            }

#pragma unroll
            for (int m = 0; m < 4; m++)
#pragma unroll
                for (int n2 = 0; n2 < 2; n2++) {
                    int coll = wn * 32 + n2 * 16 + (lane & 15);
                    float bb = b1s[cc * 128 + coll];
#pragma unroll
                    for (int r = 0; r < 4; r++) {
                        int row = wm * 64 + m * 16 + (lane >> 4) * 4 + r;
                        unsigned short hv = f2bf(wk * gelu_exact(acc1[m][n2][r] + bb));
                        *(unsigned short*)((char*)Hsw + row * 256 +
                                           ((coll * 2) ^ ((row & 7) << 4))) = hv;
                    }
                }
            __syncthreads();

#pragma unroll
            for (int ks2 = 0; ks2 < 4; ks2++) {
                bf16x8 af2[4], bf2[4];
#pragma unroll
                for (int m = 0; m < 4; m++) {
                    int row = wm * 64 + m * 16 + (lane & 15);
                    int cb = ks2 * 64 + (lane >> 4) * 16;
                    af2[m] = *(const bf16x8*)((char*)Hsw + row * 256 + (cb ^ ((row & 7) << 4)));
                }
#pragma unroll
                for (int nn = 0; nn < 4; nn++) {
                    int tile_n = wn * 4 + nn;
                    int tile_k = cc * 4 + ks2;
                    bf2[nn] = *(const bf16x8*)(W2frag + ((size_t)(tile_n * 32 + tile_k) * 64 + lane) * 8);
                }
#pragma unroll
                for (int m = 0; m < 4; m++)
#pragma unroll
                    for (int nn = 0; nn < 4; nn++)
                        acc2[m][nn] = __builtin_amdgcn_mfma_f32_16x16x32_bf16(af2[m], bf2[nn],
                                                                              acc2[m][nn], 0, 0, 0);
            }
            __syncthreads();
        }
    }

#pragma unroll
    for (int nn = 0; nn < 4; nn++) {
        int col = wn * 64 + nn * 16 + (lane & 15);
        float bb = b2[col];
#pragma unroll
        for (int m = 0; m < 4; m++) {
            int rbase = row0 + wm * 64 + m * 16 + (lane >> 4) * 4;
#pragma unroll
            for (int r = 0; r < 4; r++)
                out[(size_t)(rbase + r) * C_DIM + col] += acc2[m][nn][r] + bb;
        }
    }
}

// ------------------------------------------------------------------
extern "C" void kernel_launch(void* const* d_in, const int* in_sizes, int n_in,
                              void* d_out, int out_size, void* d_ws, size_t ws_size,
                              hipStream_t stream) {
    const float* x  = (const float*)d_in[0];
    const float* Wc = (const float*)d_in[1];
    const float* bc = (const float*)d_in[2];
    const float* W1 = (const float*)d_in[3];
    const float* b1 = (const float*)d_in[4];
    const float* W2 = (const float*)d_in[5];
    const float* b2 = (const float*)d_in[6];
    float* out = (float*)d_out;

    const size_t CONV_ELEMS = (size_t)B_DIM * T_LEN * C_DIM;     // 8M
    const size_t CONV_BYTES = CONV_ELEMS * 2;                    // 16.78 MB
    const size_t MAGS_BYTES = (size_t)B_DIM * C_DIM * 2048 * 4;  // 16.78 MB
    const size_t XT_BYTES = (size_t)B_DIM * T_LEN * C_DIM * 4;   // 33.55 MB

    // ---- fixed carve ----
    uint8_t* ws = (uint8_t*)d_ws;
    size_t off = 0;
    auto alloc = [&](size_t bytes) {
        size_t o = off;
        off = (off + bytes + 255) & ~(size_t)255;
        return o;
    };
    float* partial = (float*)(ws + alloc((size_t)B_DIM * 8 * 2048 * 4));
    int* meta_p = (int*)(ws + alloc(B_DIM * K_TOP * 4));
    float* meta_w = (float*)(ws + alloc(B_DIM * K_TOP * 4));
    unsigned short* xbf = (unsigned short*)(ws + alloc((size_t)B_DIM * T_LEN * C_DIM * 2));
    unsigned short* WcT = (unsigned short*)(ws + alloc((size_t)256 * 2304 * 2));
    unsigned short* W1frag = (unsigned short*)(ws + alloc((size_t)256 * 1024 * 2));
    unsigned short* W2frag = (unsigned short*)(ws + alloc((size_t)1024 * 256 * 2));
    unsigned short* zbuf = (unsigned short*)(ws + alloc(512));

    // ---- tiered regionA ----
    size_t remaining = (ws_size > off) ? (ws_size - off) : 0;
    uint8_t* regionA = ws + off;
    int tier;  // 2=FULL(4 convbufs), 1=MID(1 convbuf + xT), 0=MIN
    if (remaining >= 4 * CONV_BYTES) tier = 2;
    else if (remaining >= MAGS_BYTES + XT_BYTES) tier = 1;
    else tier = 0;

    float* mags = (float*)regionA;  // FFT phase (dead before conv)
    float* xT = (float*)(regionA + ((tier == 2) ? CONV_BYTES : MAGS_BYTES));
    unsigned short* convbufs = (unsigned short*)regionA;
    const int use_xT = (tier >= 1);

    // 1. out = x ; xbf = bf16(x) ; zero page
    cvt_x_kernel<<<dim3((B_DIM * T_LEN * C_DIM / 4) / 256), 256, 0, stream>>>(
        (const float4*)x, (float4*)out, (ushort4*)xbf, zbuf);

    // 2. weight prep
    transpose_cvt_kernel<<<dim3(256 / 32, 2304 / 32), 256, 0, stream>>>(Wc, WcT, 2304, 256);
    repack_frag_kernel<<<dim3(128), 256, 0, stream>>>(W1, W1frag, 256, 1024);
    repack_frag_kernel<<<dim3(128), 256, 0, stream>>>(W2, W2frag, 1024, 256);

    // 3. FFT magnitudes, reduce, top-4
    if (use_xT) {
        transpose_x_kernel<<<dim3(T_LEN / 32, C_DIM / 32, B_DIM), 256, 0, stream>>>(x, xT);
        fft_mag_kernel<<<dim3(B_DIM * C_DIM), 256, 0, stream>>>(xT, mags, 1);
    } else {
        fft_mag_kernel<<<dim3(B_DIM * C_DIM), 256, 0, stream>>>(x, mags, 0);
    }
    reduce_amps_kernel<<<dim3(2048 / 256, 8, B_DIM), 256, 0, stream>>>(mags, partial);
    topk_kernel<<<dim3(B_DIM), 256, 0, stream>>>(partial, meta_p, meta_w);

    // 4. conv (all k) then fused FF (all k)
    if (tier == 2) {
        conv_mfma_kernel<<<dim3(32, B_DIM, K_TOP), 512, 0, stream>>>(
            xbf, WcT, bc, meta_p, zbuf, convbufs, CONV_ELEMS, 0);
        fused_ff_kernel<<<dim3(B_DIM * T_LEN / 128), 512, 0, stream>>>(
            convbufs, CONV_ELEMS, W1frag, W2frag, b1, b2, meta_w, out, 0, K_TOP);
    } else {
        for (int k = 0; k < K_TOP; k++) {
            conv_mfma_kernel<<<dim3(32, B_DIM, 1), 512, 0, stream>>>(
                xbf, WcT, bc, meta_p, zbuf, convbufs, 0, k);
            fused_ff_kernel<<<dim3(B_DIM * T_LEN / 128), 512, 0, stream>>>(
                convbufs, 0, W1frag, W2frag, b1, b2, meta_w, out, k, 1);
        }
    }
}

// Round 8
// 452.318 us; speedup vs baseline: 12.0879x; 1.0599x over previous
//
#include <hip/hip_runtime.h>
#include <cstdint>
#include <cstddef>

#define T_LEN 4096
#define C_DIM 256
#define B_DIM 8
#define K_TOP 4

typedef __attribute__((ext_vector_type(8))) short bf16x8;
typedef __attribute__((ext_vector_type(4))) float f32x4;

__device__ __forceinline__ float gelu_exact(float x) {
    return 0.5f * x * (1.0f + erff(x * 0.70710678118654752f));
}

__device__ __forceinline__ unsigned short f2bf(float f) {
    uint32_t u = __float_as_uint(f);
    uint32_t r = (u + 0x7fffu + ((u >> 16) & 1u)) >> 16;
    return (unsigned short)r;
}

typedef __attribute__((address_space(3))) uint32_t lds_u32_t;
typedef __attribute__((address_space(1))) const uint32_t gbl_u32_t;

__device__ __forceinline__ void lds_load16(const void* g, void* l) {
    __builtin_amdgcn_global_load_lds((gbl_u32_t*)g, (lds_u32_t*)l, 16, 0, 0);
}

// padded LDS index for FFT: +1 float per 32
#define FPAD(i) ((i) + ((i) >> 5))

// ------------------------------------------------------------------
// out = x  AND  xbf = bf16(x)  (single read of x), plus zero page
// ------------------------------------------------------------------
__global__ __launch_bounds__(256) void cvt_x_kernel(const float4* __restrict__ x,
                                                    float4* __restrict__ out,
                                                    ushort4* __restrict__ xbf,
                                                    unsigned short* __restrict__ zbuf) {
    size_t i = (size_t)blockIdx.x * 256 + threadIdx.x;
    float4 v = x[i];
    out[i] = v;
    ushort4 o;
    o.x = f2bf(v.x); o.y = f2bf(v.y); o.z = f2bf(v.z); o.w = f2bf(v.w);
    xbf[i] = o;
    if (blockIdx.x == 0 && threadIdx.x < 256) zbuf[threadIdx.x] = 0;
}

// ------------------------------------------------------------------
// fp32 [R][C] -> bf16 transposed [C][R]   (conv weights)
// ------------------------------------------------------------------
__global__ __launch_bounds__(256) void transpose_cvt_kernel(const float* __restrict__ src,
                                                            unsigned short* __restrict__ dst,
                                                            int R, int C) {
    __shared__ float t[32][33];
    const int c0 = blockIdx.x * 32, r0 = blockIdx.y * 32;
    const int lx = threadIdx.x & 31, ly = threadIdx.x >> 5;
    for (int rr = ly; rr < 32; rr += 8) {
        int r = r0 + rr, c = c0 + lx;
        t[rr][lx] = (r < R && c < C) ? src[(size_t)r * C + c] : 0.0f;
    }
    __syncthreads();
    for (int rr = ly; rr < 32; rr += 8) {
        int c = c0 + rr, r = r0 + lx;
        if (r < R && c < C) dst[(size_t)c * R + r] = f2bf(t[lx][rr]);
    }
}

// ------------------------------------------------------------------
// fp32 src[K][N] -> bf16 MFMA B-fragment tiles (for fused FF).
// ------------------------------------------------------------------
__global__ __launch_bounds__(256) void repack_frag_kernel(const float* __restrict__ src,
                                                          unsigned short* __restrict__ dst,
                                                          int K, int N) {
    int idx = blockIdx.x * 256 + threadIdx.x;  // (tile, lane)
    int total = (N >> 4) * (K >> 5) * 64;
    if (idx >= total) return;
    int lane = idx & 63, tile = idx >> 6;
    int ktiles = K >> 5;
    int tile_n = tile / ktiles, tile_k = tile % ktiles;
    int col = tile_n * 16 + (lane & 15);
    int k0 = tile_k * 32 + (lane >> 4) * 8;
    __align__(16) unsigned short v[8];
#pragma unroll
    for (int j = 0; j < 8; j++) v[j] = f2bf(src[(size_t)(k0 + j) * N + col]);
    *(uint4*)(dst + (size_t)idx * 8) = *(const uint4*)v;
}

// ------------------------------------------------------------------
// fp32 x[b][t][c] -> xT[b][c][t]
// ------------------------------------------------------------------
__global__ __launch_bounds__(256) void transpose_x_kernel(const float* __restrict__ x,
                                                          float* __restrict__ xT) {
    __shared__ float tile[32][33];
    const int b = blockIdx.z;
    const int t0 = blockIdx.x * 32, c0 = blockIdx.y * 32;
    const int lx = threadIdx.x & 31, ly = threadIdx.x >> 5;
    const float* xp = x + (size_t)b * T_LEN * C_DIM;
    float* op = xT + (size_t)b * C_DIM * T_LEN;
    for (int rr = ly; rr < 32; rr += 8)
        tile[rr][lx] = xp[(size_t)(t0 + rr) * C_DIM + c0 + lx];
    __syncthreads();
    for (int rr = ly; rr < 32; rr += 8)
        op[(size_t)(c0 + rr) * T_LEN + t0 + lx] = tile[lx][rr];
}

// ------------------------------------------------------------------
// Per-(b,c) 4096-pt FFT, fused radix-2 stage-pairs, pad-32 LDS.
// ------------------------------------------------------------------
__global__ __launch_bounds__(256) void fft_mag_kernel(const float* __restrict__ src,
                                                      float* __restrict__ mags,
                                                      int transposed) {
    const int bx = blockIdx.x;
    const int b = bx >> 8;
    const int c = bx & 255;
    const int tid = threadIdx.x;

    __shared__ __align__(16) float re[4224];
    __shared__ __align__(16) float im[4224];
    __shared__ __align__(16) float twr[2048];
    __shared__ __align__(16) float twi[2048];

    for (int u = tid; u < 2048; u += 256) {
        float ang = -6.283185307179586f * (float)u / 4096.0f;
        float s, co;
        sincosf(ang, &s, &co);
        twr[u] = co;
        twi[u] = s;
    }
    for (int i = tid; i < 4224; i += 256) im[i] = 0.0f;

    if (transposed) {
        const float4* row = (const float4*)(src + ((size_t)(b * C_DIM + c)) * T_LEN);
        for (int e4 = tid; e4 < 1024; e4 += 256) {
            float4 v = row[e4];
            int e = e4 * 4;
            re[FPAD((int)(__brev((unsigned)(e + 0)) >> 20))] = v.x;
            re[FPAD((int)(__brev((unsigned)(e + 1)) >> 20))] = v.y;
            re[FPAD((int)(__brev((unsigned)(e + 2)) >> 20))] = v.z;
            re[FPAD((int)(__brev((unsigned)(e + 3)) >> 20))] = v.w;
        }
    } else {
        const float* xp = src + (size_t)b * T_LEN * C_DIM + c;
        for (int e = tid; e < 4096; e += 256) {
            int r = (int)(__brev((unsigned)e) >> 20);
            re[FPAD(r)] = xp[(size_t)e * C_DIM];
        }
    }
    __syncthreads();

#pragma unroll
    for (int sp = 0; sp < 6; sp++) {
        const int h = 1 << (2 * sp);
        const int t1s = 11 - 2 * sp;
        const int t2s = 10 - 2 * sp;
        for (int j = tid; j < 1024; j += 256) {
            int p = j & (h - 1);
            int G = j >> (2 * sp);
            int base = G * 4 * h + p;
            int iA = FPAD(base), iB = FPAD(base + h);
            int iC = FPAD(base + 2 * h), iD = FPAD(base + 3 * h);
            float w1r = twr[p << t1s], w1i = twi[p << t1s];
            float w2r = twr[p << t2s], w2i = twi[p << t2s];
            float Ar = re[iA], Ai = im[iA], Br = re[iB], Bi = im[iB];
            float Cr = re[iC], Ci = im[iC], Dr = re[iD], Di = im[iD];
            float tBr = w1r * Br - w1i * Bi, tBi = w1r * Bi + w1i * Br;
            float tDr = w1r * Dr - w1i * Di, tDi = w1r * Di + w1i * Dr;
            float A1r = Ar + tBr, A1i = Ai + tBi;
            float B1r = Ar - tBr, B1i = Ai - tBi;
            float C1r = Cr + tDr, C1i = Ci + tDi;
            float D1r = Cr - tDr, D1i = Ci - tDi;
            float tCr = w2r * C1r - w2i * C1i, tCi = w2r * C1i + w2i * C1r;
            float uDr = w2r * D1r - w2i * D1i, uDi = w2r * D1i + w2i * D1r;
            float vDr = uDi, vDi = -uDr;
            re[iA] = A1r + tCr; im[iA] = A1i + tCi;
            re[iC] = A1r - tCr; im[iC] = A1i - tCi;
            re[iB] = B1r + vDr; im[iB] = B1i + vDi;
            re[iD] = B1r - vDr; im[iD] = B1i - vDi;
        }
        __syncthreads();
    }

    float* mp = mags + ((size_t)(b * C_DIM + c)) * 2048;
    for (int u = tid; u < 2048; u += 256) {
        int f = FPAD(u + 1);
        mp[u] = sqrtf(re[f] * re[f] + im[f] * im[f]);
    }
}

// ------------------------------------------------------------------
// partial[b][cc][u] = sum over 32 channels of mags
// ------------------------------------------------------------------
__global__ __launch_bounds__(256) void reduce_amps_kernel(const float* __restrict__ mags,
                                                          float* __restrict__ partial) {
    const int b = blockIdx.z, cc = blockIdx.y;
    const int u = blockIdx.x * 256 + threadIdx.x;
    const float* mp = mags + ((size_t)b * C_DIM + cc * 32) * 2048 + u;
    float s = 0.0f;
    for (int c = 0; c < 32; c++) s += mp[(size_t)c * 2048];
    partial[((size_t)b * 8 + cc) * 2048 + u] = s;
}

// ------------------------------------------------------------------
// Per-batch top-4 (value desc, ties -> lower index), periods, softmax
// ------------------------------------------------------------------
__global__ __launch_bounds__(256) void topk_kernel(const float* __restrict__ partial,
                                                   int* __restrict__ meta_p,
                                                   float* __restrict__ meta_w) {
    const int b = blockIdx.x;
    const int tid = threadIdx.x;
    __shared__ float v[2048];
    __shared__ float rv[256];
    __shared__ int ri[256];
    __shared__ float topv[K_TOP];
    __shared__ int topi[K_TOP];

    for (int u = tid; u < 2048; u += 256) {
        float s = 0.0f;
        for (int cc = 0; cc < 8; cc++) s += partial[((size_t)b * 8 + cc) * 2048 + u];
        v[u] = s * (1.0f / (float)C_DIM);
    }

    for (int k = 0; k < K_TOP; k++) {
        __syncthreads();
        float bv = -1e30f;
        int bi = 2048;
        for (int u = tid; u < 2048; u += 256) {
            float val = v[u];
            if (val > bv) { bv = val; bi = u; }
        }
        rv[tid] = bv;
        ri[tid] = bi;
        __syncthreads();
        for (int s = 128; s > 0; s >>= 1) {
            if (tid < s) {
                float ov = rv[tid + s];
                int oi = ri[tid + s];
                if (ov > rv[tid] || (ov == rv[tid] && oi < ri[tid])) {
                    rv[tid] = ov;
                    ri[tid] = oi;
                }
            }
            __syncthreads();
        }
        if (tid == 0) {
            topv[k] = rv[0];
            topi[k] = ri[0];
            v[ri[0]] = -1e30f;
        }
    }
    __syncthreads();
    if (tid == 0) {
        float mx = topv[0];
        for (int k = 1; k < K_TOP; k++) mx = fmaxf(mx, topv[k]);
        float e[K_TOP], se = 0.0f;
        for (int k = 0; k < K_TOP; k++) { e[k] = expf(topv[k] - mx); se += e[k]; }
        for (int k = 0; k < K_TOP; k++) {
            int idx = topi[k];
            int d = (idx >= 1) ? idx : 1;
            int p = T_LEN / d;
            if (p < 1) p = 1;
            meta_p[b * K_TOP + k] = p;
            meta_w[b * K_TOP + k] = e[k] / se;
        }
    }
}

// ------------------------------------------------------------------
// Conv as MFMA GEMM v2 (unchanged from round 7): 128x256 tile, 512 thr,
// double-buffered 2-phase K-loop, source-permute XOR swizzle.
// ------------------------------------------------------------------
__global__ __launch_bounds__(512) void conv_mfma_kernel(const unsigned short* __restrict__ xbf,
                                                        const unsigned short* __restrict__ WcT,
                                                        const float* __restrict__ bc,
                                                        const int* __restrict__ meta_p,
                                                        const unsigned short* __restrict__ zbuf,
                                                        unsigned short* __restrict__ convbufs,
                                                        size_t conv_stride, int koff) {
    const int b = blockIdx.y;
    const int kz = blockIdx.z;
    const int n = meta_p[b * K_TOP + koff + kz];
    const int row0 = blockIdx.x * 128;
    const int tid = threadIdx.x, w = tid >> 6, lane = tid & 63;
    const int wm = w >> 2, wn = w & 3;

    __shared__ __align__(16) unsigned short Al[2][128 * 32];
    __shared__ __align__(16) unsigned short Bl[2][256 * 32];

    const int ra = tid >> 2;
    const int swz = ((tid & 3) ^ (ra & 3)) * 8;
    int ti, tj;
    {
        int t = row0 + ra;
        ti = t / n;
        tj = t - ti * n;
    }
    const unsigned short* xb = xbf + (size_t)b * T_LEN * C_DIM;
    const unsigned short* baseB0 = WcT + (size_t)ra * 2304 + swz;
    const unsigned short* baseB1 = WcT + (size_t)(ra + 128) * 2304 + swz;

    auto computeA = [&](int q) -> const unsigned short* {
        int di = q / 3 - 1, dj = q % 3 - 1;
        int ii = ti + di, jj = tj + dj;
        int tp = ii * n + jj;
        bool ok = (jj >= 0) && (jj < n) && (ii >= 0) && (tp < T_LEN);
        return ok ? (xb + (size_t)tp * C_DIM + swz) : (zbuf + swz);
    };

    f32x4 acc[4][4];
#pragma unroll
    for (int m = 0; m < 4; m++)
#pragma unroll
        for (int nn = 0; nn < 4; nn++) acc[m][nn] = (f32x4){0.f, 0.f, 0.f, 0.f};

    const unsigned short* baseA = computeA(0);
    lds_load16(baseA, &Al[0][tid * 8]);
    lds_load16(baseB0, &Bl[0][tid * 8]);
    lds_load16(baseB1, &Bl[0][4096 + tid * 8]);
    __syncthreads();

#pragma unroll 2
    for (int ks = 0; ks < 72; ks++) {
        const int cur = ks & 1;
        if (ks < 71) {
            int s = ks + 1;
            if ((s & 7) == 0) baseA = computeA(s >> 3);
            lds_load16(baseA + (s & 7) * 32, &Al[cur ^ 1][tid * 8]);
            lds_load16(baseB0 + s * 32, &Bl[cur ^ 1][tid * 8]);
            lds_load16(baseB1 + s * 32, &Bl[cur ^ 1][4096 + tid * 8]);
        }

        bf16x8 af[4], bfr[4];
#pragma unroll
        for (int m = 0; m < 4; m++) {
            int row = wm * 64 + m * 16 + (lane & 15);
            af[m] = *(const bf16x8*)((const char*)&Al[cur][0] + row * 64 +
                                     (((lane >> 4) * 16) ^ ((row & 3) << 4)));
        }
#pragma unroll
        for (int nn = 0; nn < 4; nn++) {
            int rowb = wn * 64 + nn * 16 + (lane & 15);
            bfr[nn] = *(const bf16x8*)((const char*)&Bl[cur][0] + rowb * 64 +
                                       (((lane >> 4) * 16) ^ ((rowb & 3) << 4)));
        }
#pragma unroll
        for (int m = 0; m < 4; m++)
#pragma unroll
            for (int nn = 0; nn < 4; nn++)
                acc[m][nn] = __builtin_amdgcn_mfma_f32_16x16x32_bf16(af[m], bfr[nn], acc[m][nn], 0, 0, 0);

        __syncthreads();
    }

    unsigned short* ob = convbufs + (size_t)kz * conv_stride + (size_t)b * T_LEN * C_DIM;
#pragma unroll
    for (int nn = 0; nn < 4; nn++) {
        int col = wn * 64 + nn * 16 + (lane & 15);
        float bs = bc[col];
#pragma unroll
        for (int m = 0; m < 4; m++) {
            int rbase = row0 + wm * 64 + m * 16 + (lane >> 4) * 4;
#pragma unroll
            for (int r = 0; r < 4; r++) {
                float v = acc[m][nn][r] + bs;
                ob[(size_t)(rbase + r) * C_DIM + col] = f2bf(gelu_exact(v));
            }
        }
    }
}

// ------------------------------------------------------------------
// Fused FF v2:  out[strip] += sum_k (wk*gelu(A_k@W1+b1))@W2 + b2
// 256 thr / 4 waves, 64-row strip, grid 512 (2 blocks/CU, independent
// barrier groups).  LDS 68KB: Asw[64x256] staged once per k via
// global_load_lds w/ inverse-swizzled source; Hsw double-buffered
// (one barrier per hidden chunk: write of buf[p^1] is ordered after
// barrier(cc), transitively after all reads of buf[p^1] at cc-1).
// W1/W2 read as per-lane 16B fragment tiles straight from L2.
// ------------------------------------------------------------------
__global__ __launch_bounds__(256, 2) void fused_ff_kernel(
    const unsigned short* __restrict__ convbufs, size_t conv_stride,
    const unsigned short* __restrict__ W1frag,
    const unsigned short* __restrict__ W2frag,
    const float* __restrict__ b1,
    const float* __restrict__ b2,
    const float* __restrict__ meta_w,
    float* __restrict__ out,
    int koff, int kcount) {
    const int tid = threadIdx.x;
    const int wn = tid >> 6, lane = tid & 63;
    const int row0 = blockIdx.x * 64;
    const int b = row0 >> 12;

    __shared__ __align__(16) unsigned short Asw[64 * 256];      // 32 KB
    __shared__ __align__(16) unsigned short Hsw[2][64 * 128];   // 2 x 16 KB
    __shared__ float b1s[1024];                                  // 4 KB

    for (int i = tid; i < 1024; i += 256) b1s[i] = b1[i];

    f32x4 acc2[4][4];
#pragma unroll
    for (int m = 0; m < 4; m++)
#pragma unroll
        for (int nn = 0; nn < 4; nn++) acc2[m][nn] = (f32x4){0.f, 0.f, 0.f, 0.f};

    for (int kk = koff; kk < koff + kcount; kk++) {
        const float wk = meta_w[b * K_TOP + kk];
        const unsigned short* Ag =
            convbufs + (size_t)(kk - koff) * conv_stride + (size_t)row0 * C_DIM;

        // ---- stage A strip (64x256 bf16 = 32KB) via global_load_lds,
        //      linear LDS dest + inverse-swizzled global source ----
        // (safe: all GEMM1 reads of Asw from prev k completed before the
        //  last barrier of that k; concurrent GEMM2 reads touch Hsw only)
#pragma unroll
        for (int u = 0; u < 8; u++) {
            int ch = u * 256 + tid;                       // 16B chunk id
            int row = ch >> 5;
            int cole = ((ch & 31) * 8) ^ ((row & 7) << 3);  // elem offset
            lds_load16(Ag + (size_t)row * 256 + cole, (unsigned short*)Asw + (size_t)ch * 8);
        }
        __syncthreads();  // drains global_load_lds (vmcnt) + b1s on first pass

        for (int cc = 0; cc < 8; cc++) {
            const int par = cc & 1;
            // ---- GEMM1: h chunk [64 x 128], A from LDS, W1 from global ----
            f32x4 acc1[4][2];
#pragma unroll
            for (int m = 0; m < 4; m++)
#pragma unroll
                for (int n2 = 0; n2 < 2; n2++) acc1[m][n2] = (f32x4){0.f, 0.f, 0.f, 0.f};

#pragma unroll
            for (int ks = 0; ks < 8; ks++) {
                bf16x8 af[4], bf1[2];
#pragma unroll
                for (int m = 0; m < 4; m++) {
                    int row = m * 16 + (lane & 15);
                    af[m] = *(const bf16x8*)((const char*)Asw + row * 512 +
                                             ((ks * 64 + (lane >> 4) * 16) ^ ((row & 7) << 4)));
                }
#pragma unroll
                for (int n2 = 0; n2 < 2; n2++) {
                    int tile_n = cc * 8 + wn * 2 + n2;
                    bf1[n2] = *(const bf16x8*)(W1frag + ((size_t)(tile_n * 8 + ks) * 64 + lane) * 8);
                }
#pragma unroll
                for (int m = 0; m < 4; m++)
#pragma unroll
                    for (int n2 = 0; n2 < 2; n2++)
                        acc1[m][n2] = __builtin_amdgcn_mfma_f32_16x16x32_bf16(af[m], bf1[n2],
                                                                              acc1[m][n2], 0, 0, 0);
            }

            // ---- gelu + wk-scale -> Hsw[par] (bf16, swizzled) ----
#pragma unroll
            for (int m = 0; m < 4; m++)
#pragma unroll
                for (int n2 = 0; n2 < 2; n2++) {
                    int coll = wn * 32 + n2 * 16 + (lane & 15);
                    float bb = b1s[cc * 128 + coll];
#pragma unroll
                    for (int r = 0; r < 4; r++) {
                        int row = m * 16 + (lane >> 4) * 4 + r;
                        unsigned short hv = f2bf(wk * gelu_exact(acc1[m][n2][r] + bb));
                        *(unsigned short*)((char*)&Hsw[par][0] + row * 256 +
                                           ((coll * 2) ^ ((row & 7) << 4))) = hv;
                    }
                }
            __syncthreads();  // the ONE barrier per chunk

            // ---- GEMM2: acc2 += h_chunk @ W2chunk ----
#pragma unroll
            for (int ks2 = 0; ks2 < 4; ks2++) {
                bf16x8 af2[4], bf2[4];
#pragma unroll
                for (int m = 0; m < 4; m++) {
                    int row = m * 16 + (lane & 15);
                    af2[m] = *(const bf16x8*)((const char*)&Hsw[par][0] + row * 256 +
                                              ((ks2 * 64 + (lane >> 4) * 16) ^ ((row & 7) << 4)));
                }
#pragma unroll
                for (int nn = 0; nn < 4; nn++) {
                    int tile_n = wn * 4 + nn;
                    int tile_k = cc * 4 + ks2;
                    bf2[nn] = *(const bf16x8*)(W2frag + ((size_t)(tile_n * 32 + tile_k) * 64 + lane) * 8);
                }
#pragma unroll
                for (int m = 0; m < 4; m++)
#pragma unroll
                    for (int nn = 0; nn < 4; nn++)
                        acc2[m][nn] = __builtin_amdgcn_mfma_f32_16x16x32_bf16(af2[m], bf2[nn],
                                                                              acc2[m][nn], 0, 0, 0);
            }
            // no barrier here: next chunk writes Hsw[par^1], whose cc-1
            // readers are ordered before the barrier above.
        }
    }

    // ---- epilogue: out += acc2 + b2  (sum_k wk == 1) ----
#pragma unroll
    for (int nn = 0; nn < 4; nn++) {
        int col = wn * 64 + nn * 16 + (lane & 15);
        float bb = b2[col];
#pragma unroll
        for (int m = 0; m < 4; m++) {
            int rbase = row0 + m * 16 + (lane >> 4) * 4;
#pragma unroll
            for (int r = 0; r < 4; r++)
                out[(size_t)(rbase + r) * C_DIM + col] += acc2[m][nn][r] + bb;
        }
    }
}

// ------------------------------------------------------------------
extern "C" void kernel_launch(void* const* d_in, const int* in_sizes, int n_in,
                              void* d_out, int out_size, void* d_ws, size_t ws_size,
                              hipStream_t stream) {
    const float* x  = (const float*)d_in[0];
    const float* Wc = (const float*)d_in[1];
    const float* bc = (const float*)d_in[2];
    const float* W1 = (const float*)d_in[3];
    const float* b1 = (const float*)d_in[4];
    const float* W2 = (const float*)d_in[5];
    const float* b2 = (const float*)d_in[6];
    float* out = (float*)d_out;

    const size_t CONV_ELEMS = (size_t)B_DIM * T_LEN * C_DIM;     // 8M
    const size_t CONV_BYTES = CONV_ELEMS * 2;                    // 16.78 MB
    const size_t MAGS_BYTES = (size_t)B_DIM * C_DIM * 2048 * 4;  // 16.78 MB
    const size_t XT_BYTES = (size_t)B_DIM * T_LEN * C_DIM * 4;   // 33.55 MB

    // ---- fixed carve ----
    uint8_t* ws = (uint8_t*)d_ws;
    size_t off = 0;
    auto alloc = [&](size_t bytes) {
        size_t o = off;
        off = (off + bytes + 255) & ~(size_t)255;
        return o;
    };
    float* partial = (float*)(ws + alloc((size_t)B_DIM * 8 * 2048 * 4));
    int* meta_p = (int*)(ws + alloc(B_DIM * K_TOP * 4));
    float* meta_w = (float*)(ws + alloc(B_DIM * K_TOP * 4));
    unsigned short* xbf = (unsigned short*)(ws + alloc((size_t)B_DIM * T_LEN * C_DIM * 2));
    unsigned short* WcT = (unsigned short*)(ws + alloc((size_t)256 * 2304 * 2));
    unsigned short* W1frag = (unsigned short*)(ws + alloc((size_t)256 * 1024 * 2));
    unsigned short* W2frag = (unsigned short*)(ws + alloc((size_t)1024 * 256 * 2));
    unsigned short* zbuf = (unsigned short*)(ws + alloc(512));

    // ---- tiered regionA ----
    size_t remaining = (ws_size > off) ? (ws_size - off) : 0;
    uint8_t* regionA = ws + off;
    int tier;  // 2=FULL(4 convbufs), 1=MID(1 convbuf + xT), 0=MIN
    if (remaining >= 4 * CONV_BYTES) tier = 2;
    else if (remaining >= MAGS_BYTES + XT_BYTES) tier = 1;
    else tier = 0;

    float* mags = (float*)regionA;  // FFT phase (dead before conv)
    float* xT = (float*)(regionA + ((tier == 2) ? CONV_BYTES : MAGS_BYTES));
    unsigned short* convbufs = (unsigned short*)regionA;
    const int use_xT = (tier >= 1);

    // 1. out = x ; xbf = bf16(x) ; zero page
    cvt_x_kernel<<<dim3((B_DIM * T_LEN * C_DIM / 4) / 256), 256, 0, stream>>>(
        (const float4*)x, (float4*)out, (ushort4*)xbf, zbuf);

    // 2. weight prep
    transpose_cvt_kernel<<<dim3(256 / 32, 2304 / 32), 256, 0, stream>>>(Wc, WcT, 2304, 256);
    repack_frag_kernel<<<dim3(128), 256, 0, stream>>>(W1, W1frag, 256, 1024);
    repack_frag_kernel<<<dim3(128), 256, 0, stream>>>(W2, W2frag, 1024, 256);

    // 3. FFT magnitudes, reduce, top-4
    if (use_xT) {
        transpose_x_kernel<<<dim3(T_LEN / 32, C_DIM / 32, B_DIM), 256, 0, stream>>>(x, xT);
        fft_mag_kernel<<<dim3(B_DIM * C_DIM), 256, 0, stream>>>(xT, mags, 1);
    } else {
        fft_mag_kernel<<<dim3(B_DIM * C_DIM), 256, 0, stream>>>(x, mags, 0);
    }
    reduce_amps_kernel<<<dim3(2048 / 256, 8, B_DIM), 256, 0, stream>>>(mags, partial);
    topk_kernel<<<dim3(B_DIM), 256, 0, stream>>>(partial, meta_p, meta_w);

    // 4. conv (all k) then fused FF (all k)
    if (tier == 2) {
        conv_mfma_kernel<<<dim3(32, B_DIM, K_TOP), 512, 0, stream>>>(
            xbf, WcT, bc, meta_p, zbuf, convbufs, CONV_ELEMS, 0);
        fused_ff_kernel<<<dim3(B_DIM * T_LEN / 64), 256, 0, stream>>>(
            convbufs, CONV_ELEMS, W1frag, W2frag, b1, b2, meta_w, out, 0, K_TOP);
    } else {
        for (int k = 0; k < K_TOP; k++) {
            conv_mfma_kernel<<<dim3(32, B_DIM, 1), 512, 0, stream>>>(
                xbf, WcT, bc, meta_p, zbuf, convbufs, 0, k);
            fused_ff_kernel<<<dim3(B_DIM * T_LEN / 64), 256, 0, stream>>>(
                convbufs, 0, W1frag, W2frag, b1, b2, meta_w, out, k, 1);
        }
    }
}